// Round 1
// baseline (9378.510 us; speedup 1.0000x reference)
//
#include <hip/hip_runtime.h>
#include <hip/hip_bf16.h>
#include <math.h>

// Problem constants (match reference)
#define H_DIM 1024
#define NHEAD 16
#define HDm   64
#define SEQ   2048
#define BATCH 2
#define RDIM  64
#define MDIM  4096
#define ALPHA_C 0.5f
#define BETA_C  0.1f
#define GAMMA_C 0.95f

__device__ __forceinline__ float gelu_exact(float x) {
  return 0.5f * x * (1.f + erff(x * 0.70710678118654752f));
}
__device__ __forceinline__ float phi_elu(float x) {   // elu(x)+1
  return x > 0.f ? x + 1.f : __expf(x);
}
__device__ __forceinline__ float wave_sum(float v) {
  #pragma unroll
  for (int o = 32; o > 0; o >>= 1) v += __shfl_xor(v, o, 64);
  return v;
}
__device__ __forceinline__ float wave_max(float v) {
  #pragma unroll
  for (int o = 32; o > 0; o >>= 1) v = fmaxf(v, __shfl_xor(v, o, 64));
  return v;
}

// ---------------- LayerNorm: one block per row (H=1024, 256 thr x float4) ----
__global__ __launch_bounds__(256) void ln_kernel(
    const float* __restrict__ x, const float* __restrict__ g,
    const float* __restrict__ bt, float* __restrict__ out) {
  __shared__ float lds[4];
  const int row = blockIdx.x;
  const int tid = threadIdx.x;
  const float4 v = reinterpret_cast<const float4*>(x + (size_t)row * H_DIM)[tid];
  float s = (v.x + v.y) + (v.z + v.w);
  s = wave_sum(s);
  if ((tid & 63) == 0) lds[tid >> 6] = s;
  __syncthreads();
  const float mu = (lds[0] + lds[1] + lds[2] + lds[3]) * (1.f / H_DIM);
  __syncthreads();
  float4 d;
  d.x = v.x - mu; d.y = v.y - mu; d.z = v.z - mu; d.w = v.w - mu;
  float s2 = (d.x * d.x + d.y * d.y) + (d.z * d.z + d.w * d.w);
  s2 = wave_sum(s2);
  if ((tid & 63) == 0) lds[tid >> 6] = s2;
  __syncthreads();
  const float var = (lds[0] + lds[1] + lds[2] + lds[3]) * (1.f / H_DIM);
  const float rs = rsqrtf(var + 1e-5f);
  const float4 gg = reinterpret_cast<const float4*>(g)[tid];
  const float4 bb = reinterpret_cast<const float4*>(bt)[tid];
  float4 o;
  o.x = d.x * rs * gg.x + bb.x;
  o.y = d.y * rs * gg.y + bb.y;
  o.z = d.z * rs * gg.z + bb.z;
  o.w = d.w * rs * gg.w + bb.w;
  reinterpret_cast<float4*>(out + (size_t)row * H_DIM)[tid] = o;
}

// ---------------- Generic fp32 tiled GEMM:  C = act(A@B + bias) + R ---------
// EPI: 0 = none, 1 = elu+1, 2 = exact gelu.  256 threads, 16x16 thread grid.
template <int BM, int BN, int BK, int EPI, bool RES>
__global__ __launch_bounds__(256) void gemm_kernel(
    const float* __restrict__ A, int lda,
    const float* __restrict__ B, int ldb,
    const float* __restrict__ bias,
    const float* __restrict__ Rp, int ldr,
    float* __restrict__ C, int ldc,
    int M, int N, int K) {
  constexpr int TM = BM / 16, TN = BN / 16;
  __shared__ float As[BK][BM + 4];
  __shared__ float Bs[BK][BN + 4];
  const int tid = threadIdx.x;
  const int tx = tid & 15, ty = tid >> 4;
  const int m0 = blockIdx.y * BM, n0 = blockIdx.x * BN;
  float acc[TM][TN];
  #pragma unroll
  for (int i = 0; i < TM; ++i)
    #pragma unroll
    for (int j = 0; j < TN; ++j) acc[i][j] = 0.f;

  for (int k0 = 0; k0 < K; k0 += BK) {
    // A tile (BM x BK): float4 along K, transposed into As[k][m]
    #pragma unroll
    for (int i = tid; i < BM * BK / 4; i += 256) {
      const int m = i / (BK / 4);
      const int kq = (i % (BK / 4)) * 4;
      const int gm = m0 + m;
      float4 av = make_float4(0.f, 0.f, 0.f, 0.f);
      if (gm < M) av = *reinterpret_cast<const float4*>(A + (size_t)gm * lda + k0 + kq);
      As[kq + 0][m] = av.x;
      As[kq + 1][m] = av.y;
      As[kq + 2][m] = av.z;
      As[kq + 3][m] = av.w;
    }
    // B tile (BK x BN): float4 along N
    #pragma unroll
    for (int i = tid; i < BK * BN / 4; i += 256) {
      const int kk = i / (BN / 4);
      const int n = (i % (BN / 4)) * 4;
      const int gn = n0 + n;
      float4 bv = make_float4(0.f, 0.f, 0.f, 0.f);
      if (gn < N) bv = *reinterpret_cast<const float4*>(B + (size_t)(k0 + kk) * ldb + gn);
      *reinterpret_cast<float4*>(&Bs[kk][n]) = bv;
    }
    __syncthreads();
    #pragma unroll
    for (int kk = 0; kk < BK; ++kk) {
      float a[TM], b[TN];
      #pragma unroll
      for (int i = 0; i < TM; ++i) a[i] = As[kk][ty * TM + i];
      #pragma unroll
      for (int j = 0; j < TN; ++j) b[j] = Bs[kk][tx * TN + j];
      #pragma unroll
      for (int i = 0; i < TM; ++i)
        #pragma unroll
        for (int j = 0; j < TN; ++j) acc[i][j] = fmaf(a[i], b[j], acc[i][j]);
    }
    __syncthreads();
  }
  #pragma unroll
  for (int i = 0; i < TM; ++i) {
    const int gm = m0 + ty * TM + i;
    if (gm >= M) continue;
    #pragma unroll
    for (int j = 0; j < TN; ++j) {
      const int gn = n0 + tx * TN + j;
      if (gn >= N) continue;
      float c = acc[i][j];
      if (bias) c += bias[gn];
      if (EPI == 1) c = phi_elu(c);
      else if (EPI == 2) c = gelu_exact(c);
      if (RES) c += Rp[(size_t)gm * ldr + gn];
      C[(size_t)gm * ldc + gn] = c;
    }
  }
}

// ---------------- Flash attention fp32 (causal + pad mask) ------------------
// grid (SEQ/4, NHEAD, BATCH), 256 thr = 4 waves; wave w owns q-row 4*bx+w,
// lane d accumulates ctx[d]. K/V tiles of 64 staged in LDS (pad 66: 2-way max).
__global__ __launch_bounds__(256) void attn_kernel(
    const float* __restrict__ qkv, const int* __restrict__ amask,
    float* __restrict__ ctx) {
  const int tid = threadIdx.x, lane = tid & 63, wave = tid >> 6;
  const int bx = blockIdx.x, head = blockIdx.y, b = blockIdx.z;
  const int rq = bx * 4 + wave;
  __shared__ float ks[64][66], vs[64][66], qs[4][64], ps[4][64];
  const size_t qbase = ((size_t)b * SEQ) * (3 * H_DIM) + (size_t)head * HDm;
  qs[wave][lane] = qkv[qbase + (size_t)rq * (3 * H_DIM) + lane];
  float o = 0.f, m = -INFINITY, l = 0.f;
  const int ntiles = (bx * 4 + 3) / 64 + 1;
  for (int tile = 0; tile < ntiles; ++tile) {
    const int kb = tile * 64;
    __syncthreads();
    #pragma unroll
    for (int it = 0; it < 8; ++it) {
      const int idx = tid + it * 256;          // 64 rows x 32 float2
      const int row = idx >> 5, c = (idx & 31) * 2;
      const float* gp = qkv + qbase + (size_t)(kb + row) * (3 * H_DIM) + H_DIM + c;
      const float2 kf = *reinterpret_cast<const float2*>(gp);
      const float2 vf = *reinterpret_cast<const float2*>(gp + H_DIM);
      ks[row][c] = kf.x; ks[row][c + 1] = kf.y;
      vs[row][c] = vf.x; vs[row][c + 1] = vf.y;
    }
    __syncthreads();
    // scores: lane j handles key kb+j
    float sc = 0.f;
    #pragma unroll
    for (int d = 0; d < 64; ++d) sc += qs[wave][d] * ks[lane][d];
    const int kg = kb + lane;
    const bool valid = (kg <= rq) && (amask[b * SEQ + kg] != 0);
    sc = valid ? sc * 0.125f : -INFINITY;
    const float mt = wave_max(sc);
    const float mn = fmaxf(m, mt);
    const float corr = __expf(m - mn);   // m=-inf first tile -> 0
    const float pj = valid ? __expf(sc - mn) : 0.f;
    const float lsum = wave_sum(pj);
    l = l * corr + lsum;
    o = o * corr;
    m = mn;
    ps[wave][lane] = pj;
    __syncthreads();
    #pragma unroll
    for (int j = 0; j < 64; ++j) o = fmaf(ps[wave][j], vs[j][lane], o);
  }
  ctx[((size_t)b * SEQ + rq) * H_DIM + head * HDm + lane] = o / l;
}

// ---------------- Fast-weights homeostatic scan -----------------------------
// One block per batch; thread owns column h; F[64] in registers (un-normalized
// A_t; scale folded into next decay coeff). Only the Frobenius sum needs a
// block reduction; q^T F is thread-local.
__global__ __launch_bounds__(1024) void scan_kernel(
    const float* __restrict__ qkv, const float* __restrict__ qr,
    const float* __restrict__ kr, float* __restrict__ y) {
  const int b = blockIdx.x;
  const int h = threadIdx.x;
  const int lane = h & 63, wave = h >> 6;
  float A[64];
  #pragma unroll
  for (int r = 0; r < 64; ++r) A[r] = 0.f;
  __shared__ float red[16];
  float gcoef = GAMMA_C;
  const float* vbase = qkv + (size_t)b * SEQ * (3 * H_DIM) + 2 * H_DIM + h;
  const float* krow = kr + (size_t)b * SEQ * RDIM;
  const float* qrow = qr + (size_t)b * SEQ * RDIM;
  float* yrow = y + (size_t)b * SEQ * H_DIM + h;
  for (int t = 0; t < SEQ; ++t) {
    const float v = vbase[(size_t)t * (3 * H_DIM)];
    const float av = ALPHA_C * v;
    const float* kt = krow + t * RDIM;   // wave-uniform -> scalar loads
    const float* qt = qrow + t * RDIM;
    float sq = 0.f, p = 0.f;
    #pragma unroll
    for (int r = 0; r < 64; ++r) {
      const float a = gcoef * A[r] + kt[r] * av;
      A[r] = a;
      sq += a * a;
      p += qt[r] * a;
    }
    sq = wave_sum(sq);
    if (lane == 0) red[wave] = sq;
    __syncthreads();
    float tot = 0.f;
    #pragma unroll
    for (int i = 0; i < 16; ++i) tot += red[i];
    const float s = 1.f / (1.f + BETA_C * sqrtf(tot));
    yrow[(size_t)t * H_DIM] = s * p;
    gcoef = GAMMA_C * s;
    __syncthreads();
  }
}

// ---------------- launch ----------------------------------------------------
extern "C" void kernel_launch(void* const* d_in, const int* in_sizes, int n_in,
                              void* d_out, int out_size, void* d_ws, size_t ws_size,
                              hipStream_t stream) {
  const float* x      = (const float*)d_in[0];
  const int*   amask  = (const int*)d_in[1];
  const float* ln1_g  = (const float*)d_in[2];
  const float* ln1_b  = (const float*)d_in[3];
  const float* qkv_w  = (const float*)d_in[4];
  const float* qkv_b  = (const float*)d_in[5];
  const float* out_w  = (const float*)d_in[6];
  const float* out_b  = (const float*)d_in[7];
  const float* fh_wq  = (const float*)d_in[8];
  const float* fh_wk  = (const float*)d_in[9];
  const float* fh_wo  = (const float*)d_in[10];
  const float* ln2_g  = (const float*)d_in[11];
  const float* ln2_b  = (const float*)d_in[12];
  const float* mlp_w1 = (const float*)d_in[13];
  const float* mlp_b1 = (const float*)d_in[14];
  const float* mlp_w2 = (const float*)d_in[15];
  const float* mlp_b2 = (const float*)d_in[16];
  float* out = (float*)d_out;
  float* ws  = (float*)d_ws;

  const int ROWS = BATCH * SEQ;  // 4096
  // Workspace layout (floats). g1 (4096x4096 = 16,777,216) exactly reuses
  // the dead qkv+h1 region [0, 16777216).
  float* qkv = ws;                    // 4096*3072 = 12,582,912
  float* h1  = ws + 12582912;         // 4,194,304 (reused as ctx)
  float* ctx = h1;
  float* x1  = ws + 16777216;         // 4,194,304
  float* qr  = ws + 20971520;         // 262,144
  float* kr  = ws + 21233664;         // 262,144
  float* yy  = ws + 21495808;         // 4,194,304
  float* x2  = ws + 25690112;         // 4,194,304
  float* h2  = ws + 29884416;         // 4,194,304  (total 34,078,720 floats)
  float* g1  = ws;

  // 1) h1 = LN1(x)
  ln_kernel<<<ROWS, 256, 0, stream>>>(x, ln1_g, ln1_b, h1);
  // 2) qkv = h1 @ qkv_w + qkv_b
  gemm_kernel<128, 128, 16, 0, false><<<dim3(3072 / 128, ROWS / 128), 256, 0, stream>>>(
      h1, H_DIM, qkv_w, 3 * H_DIM, qkv_b, nullptr, 0, qkv, 3 * H_DIM, ROWS, 3 * H_DIM, H_DIM);
  // 3) ctx = causal attention
  attn_kernel<<<dim3(SEQ / 4, NHEAD, BATCH), 256, 0, stream>>>(qkv, amask, ctx);
  // 4) x1 = x + ctx @ out_w + out_b
  gemm_kernel<128, 128, 16, 0, true><<<dim3(1024 / 128, ROWS / 128), 256, 0, stream>>>(
      ctx, H_DIM, out_w, H_DIM, out_b, x, H_DIM, x1, H_DIM, ROWS, H_DIM, H_DIM);
  // 5) qr = phi(q @ fh_wq), kr = phi(k @ fh_wk)   (q,k are qkv column slices)
  gemm_kernel<128, 64, 16, 1, false><<<dim3(1, ROWS / 128), 256, 0, stream>>>(
      qkv, 3 * H_DIM, fh_wq, RDIM, nullptr, nullptr, 0, qr, RDIM, ROWS, RDIM, H_DIM);
  gemm_kernel<128, 64, 16, 1, false><<<dim3(1, ROWS / 128), 256, 0, stream>>>(
      qkv + H_DIM, 3 * H_DIM, fh_wk, RDIM, nullptr, nullptr, 0, kr, RDIM, ROWS, RDIM, H_DIM);
  // 6) yy = homeostatic fast-weight scan
  scan_kernel<<<BATCH, 1024, 0, stream>>>(qkv, qr, kr, yy);
  // 7) x2 = x1 + yy @ fh_wo
  gemm_kernel<128, 128, 16, 0, true><<<dim3(1024 / 128, ROWS / 128), 256, 0, stream>>>(
      yy, H_DIM, fh_wo, H_DIM, nullptr, x1, H_DIM, x2, H_DIM, ROWS, H_DIM, H_DIM);
  // 8) h2 = LN2(x2)
  ln_kernel<<<ROWS, 256, 0, stream>>>(x2, ln2_g, ln2_b, h2);
  // 9) g1 = gelu(h2 @ mlp_w1 + mlp_b1)
  gemm_kernel<128, 128, 16, 2, false><<<dim3(4096 / 128, ROWS / 128), 256, 0, stream>>>(
      h2, H_DIM, mlp_w1, MDIM, mlp_b1, nullptr, 0, g1, MDIM, ROWS, MDIM, H_DIM);
  // 10) out = x2 + g1 @ mlp_w2 + mlp_b2
  gemm_kernel<128, 128, 16, 0, true><<<dim3(1024 / 128, ROWS / 128), 256, 0, stream>>>(
      g1, MDIM, mlp_w2, H_DIM, mlp_b2, x2, H_DIM, out, H_DIM, ROWS, H_DIM, MDIM);
}

// Round 5
// 3779.956 us; speedup vs baseline: 2.4811x; 2.4811x over previous
//
#include <hip/hip_runtime.h>
#include <hip/hip_bf16.h>
#include <math.h>

// Problem constants (match reference)
#define H_DIM 1024
#define NHEAD 16
#define HDm   64
#define SEQ   2048
#define BATCH 2
#define RDIM  64
#define MDIM  4096
#define ALPHA_C 0.5f
#define BETA_C  0.1f
#define GAMMA_C 0.95f
#define LNGAMMA (-0.051293294387550533f)
#define BAND 256

typedef __attribute__((ext_vector_type(8))) short bfrag;   // 8 bf16 (4 VGPRs)
typedef __attribute__((ext_vector_type(4))) float facc;    // 4 fp32

__device__ __forceinline__ float gelu_exact(float x) {
  return 0.5f * x * (1.f + erff(x * 0.70710678118654752f));
}
__device__ __forceinline__ float phi_elu(float x) {   // elu(x)+1
  return x > 0.f ? x + 1.f : __expf(x);
}
__device__ __forceinline__ float wave_sum(float v) {
  #pragma unroll
  for (int o = 32; o > 0; o >>= 1) v += __shfl_xor(v, o, 64);
  return v;
}
__device__ __forceinline__ float wave_max(float v) {
  #pragma unroll
  for (int o = 32; o > 0; o >>= 1) v = fmaxf(v, __shfl_xor(v, o, 64));
  return v;
}
__device__ __forceinline__ unsigned short f2bf(float f) {   // RNE fp32->bf16
  unsigned int u = __float_as_uint(f);
  u += 0x7fffu + ((u >> 16) & 1u);
  return (unsigned short)(u >> 16);
}
__device__ __forceinline__ float bf2f(unsigned short s) {
  return __uint_as_float(((unsigned int)s) << 16);
}

// ---------------- LayerNorm: one block per row (H=1024, 256 thr x float4) ----
__global__ __launch_bounds__(256) void ln_kernel(
    const float* __restrict__ x, const float* __restrict__ g,
    const float* __restrict__ bt, float* __restrict__ out) {
  __shared__ float lds[4];
  const int row = blockIdx.x;
  const int tid = threadIdx.x;
  const float4 v = reinterpret_cast<const float4*>(x + (size_t)row * H_DIM)[tid];
  float s = (v.x + v.y) + (v.z + v.w);
  s = wave_sum(s);
  if ((tid & 63) == 0) lds[tid >> 6] = s;
  __syncthreads();
  const float mu = (lds[0] + lds[1] + lds[2] + lds[3]) * (1.f / H_DIM);
  __syncthreads();
  float4 d;
  d.x = v.x - mu; d.y = v.y - mu; d.z = v.z - mu; d.w = v.w - mu;
  float s2 = (d.x * d.x + d.y * d.y) + (d.z * d.z + d.w * d.w);
  s2 = wave_sum(s2);
  if ((tid & 63) == 0) lds[tid >> 6] = s2;
  __syncthreads();
  const float var = (lds[0] + lds[1] + lds[2] + lds[3]) * (1.f / H_DIM);
  const float rs = rsqrtf(var + 1e-5f);
  const float4 gg = reinterpret_cast<const float4*>(g)[tid];
  const float4 bb = reinterpret_cast<const float4*>(bt)[tid];
  float4 o;
  o.x = d.x * rs * gg.x + bb.x;
  o.y = d.y * rs * gg.y + bb.y;
  o.z = d.z * rs * gg.z + bb.z;
  o.w = d.w * rs * gg.w + bb.w;
  reinterpret_cast<float4*>(out + (size_t)row * H_DIM)[tid] = o;
}

// ---------------- Split-bf16 MFMA GEMM: C = act(A@B + bias) + R -------------
// fp32 in/out; each fp32 split to hi/lo bf16 on the fly; 3 MFMA per product
// (hi*hi + hi*lo + lo*hi) => ~2^-17 relative error. 128x128 tile, BK=32,
// 256 thr = 4 waves in 2x2, each wave 64x64 via 4x4 16x16x32 fragments.
// Requires M,N %128==0, K %32==0 (true for all call sites).
// A/B frag k-map: logical k = (lane>>4)*8 + j for BOTH operands (any shared
// bijection is correct regardless of the HW's internal k-order).
// C/D layout (HW-verified): col = lane&15, row = (lane>>4)*4 + reg.
#define LP 40   // LDS row pitch in ushorts (32 used + 8 pad -> 80B rows)
template <int EPI, bool RES>
__global__ __launch_bounds__(256) void mgemm_kernel(
    const float* __restrict__ A, int lda,
    const float* __restrict__ B, int ldb,
    const float* __restrict__ bias,
    const float* __restrict__ Rp, int ldr,
    float* __restrict__ C, int ldc,
    int M, int N, int K) {
  __shared__ unsigned short Ah[128 * LP], Al[128 * LP];
  __shared__ unsigned short Bh[128 * LP], Bl[128 * LP];
  const int tid = threadIdx.x;
  const int lane = tid & 63, wv = tid >> 6;
  const int wr = wv >> 1, wc = wv & 1;
  const int g = lane >> 4, lr = lane & 15;
  const int m0 = blockIdx.y * 128, n0 = blockIdx.x * 128;
  facc acc[4][4];
  #pragma unroll
  for (int i = 0; i < 4; ++i)
    #pragma unroll
    for (int j = 0; j < 4; ++j) acc[i][j] = (facc)(0.f);

  for (int k0 = 0; k0 < K; k0 += 32) {
    __syncthreads();
    // stage A tile: 128 m x 32 k; thread: (m, 4 consecutive k) via float4
    #pragma unroll
    for (int it = 0; it < 4; ++it) {
      const int i = tid + it * 256;
      const int m = i >> 3, q = i & 7;
      const float4 a4 = *reinterpret_cast<const float4*>(
          A + (size_t)(m0 + m) * lda + k0 + q * 4);
      ushort4 hi, lo;
      hi.x = f2bf(a4.x); lo.x = f2bf(a4.x - bf2f(hi.x));
      hi.y = f2bf(a4.y); lo.y = f2bf(a4.y - bf2f(hi.y));
      hi.z = f2bf(a4.z); lo.z = f2bf(a4.z - bf2f(hi.z));
      hi.w = f2bf(a4.w); lo.w = f2bf(a4.w - bf2f(hi.w));
      *reinterpret_cast<ushort4*>(&Ah[m * LP + q * 4]) = hi;
      *reinterpret_cast<ushort4*>(&Al[m * LP + q * 4]) = lo;
    }
    // stage B tile: 32 k x 128 n; thread: (n, 4 consecutive k), coalesced rows
    #pragma unroll
    for (int it = 0; it < 4; ++it) {
      const int i = tid + it * 256;
      const int n = i & 127, kc = (i >> 7) * 4;
      const float* bp = B + (size_t)(k0 + kc) * ldb + n0 + n;
      const float b0 = bp[0];
      const float b1 = bp[(size_t)ldb];
      const float b2 = bp[(size_t)2 * ldb];
      const float b3 = bp[(size_t)3 * ldb];
      ushort4 hi, lo;
      hi.x = f2bf(b0); lo.x = f2bf(b0 - bf2f(hi.x));
      hi.y = f2bf(b1); lo.y = f2bf(b1 - bf2f(hi.y));
      hi.z = f2bf(b2); lo.z = f2bf(b2 - bf2f(hi.z));
      hi.w = f2bf(b3); lo.w = f2bf(b3 - bf2f(hi.w));
      *reinterpret_cast<ushort4*>(&Bh[n * LP + kc]) = hi;
      *reinterpret_cast<ushort4*>(&Bl[n * LP + kc]) = lo;
    }
    __syncthreads();
    bfrag ah[4], al[4], bh[4], bl[4];
    #pragma unroll
    for (int mi = 0; mi < 4; ++mi) {
      const int r = wr * 64 + mi * 16 + lr;
      ah[mi] = *reinterpret_cast<const bfrag*>(&Ah[r * LP + g * 8]);
      al[mi] = *reinterpret_cast<const bfrag*>(&Al[r * LP + g * 8]);
    }
    #pragma unroll
    for (int nj = 0; nj < 4; ++nj) {
      const int c = wc * 64 + nj * 16 + lr;
      bh[nj] = *reinterpret_cast<const bfrag*>(&Bh[c * LP + g * 8]);
      bl[nj] = *reinterpret_cast<const bfrag*>(&Bl[c * LP + g * 8]);
    }
    #pragma unroll
    for (int mi = 0; mi < 4; ++mi)
      #pragma unroll
      for (int nj = 0; nj < 4; ++nj) {
        acc[mi][nj] = __builtin_amdgcn_mfma_f32_16x16x32_bf16(
            ah[mi], bh[nj], acc[mi][nj], 0, 0, 0);
        acc[mi][nj] = __builtin_amdgcn_mfma_f32_16x16x32_bf16(
            ah[mi], bl[nj], acc[mi][nj], 0, 0, 0);
        acc[mi][nj] = __builtin_amdgcn_mfma_f32_16x16x32_bf16(
            al[mi], bh[nj], acc[mi][nj], 0, 0, 0);
      }
  }
  // epilogue: C/D mapping col=lane&15, row=(lane>>4)*4+reg
  #pragma unroll
  for (int mi = 0; mi < 4; ++mi) {
    const int row0 = m0 + wr * 64 + mi * 16 + g * 4;
    #pragma unroll
    for (int nj = 0; nj < 4; ++nj) {
      const int col = n0 + wc * 64 + nj * 16 + lr;
      const float bs = bias ? bias[col] : 0.f;
      #pragma unroll
      for (int r = 0; r < 4; ++r) {
        float cv = acc[mi][nj][r] + bs;
        if (EPI == 1) cv = phi_elu(cv);
        else if (EPI == 2) cv = gelu_exact(cv);
        if (RES) cv += Rp[(size_t)(row0 + r) * ldr + col];
        C[(size_t)(row0 + r) * ldc + col] = cv;
      }
    }
  }
}

// ---------------- Generic fp32 tiled GEMM (small shapes: qr/kr) ------------
template <int BM, int BN, int BK, int EPI, bool RES>
__global__ __launch_bounds__(256) void gemm_kernel(
    const float* __restrict__ A, int lda,
    const float* __restrict__ B, int ldb,
    const float* __restrict__ bias,
    const float* __restrict__ Rp, int ldr,
    float* __restrict__ C, int ldc,
    int M, int N, int K) {
  constexpr int TM = BM / 16, TN = BN / 16;
  __shared__ float As[BK][BM + 4];
  __shared__ float Bs[BK][BN + 4];
  const int tid = threadIdx.x;
  const int tx = tid & 15, ty = tid >> 4;
  const int m0 = blockIdx.y * BM, n0 = blockIdx.x * BN;
  float acc[TM][TN];
  #pragma unroll
  for (int i = 0; i < TM; ++i)
    #pragma unroll
    for (int j = 0; j < TN; ++j) acc[i][j] = 0.f;

  for (int k0 = 0; k0 < K; k0 += BK) {
    #pragma unroll
    for (int i = tid; i < BM * BK / 4; i += 256) {
      const int m = i / (BK / 4);
      const int kq = (i % (BK / 4)) * 4;
      const int gm = m0 + m;
      float4 av = make_float4(0.f, 0.f, 0.f, 0.f);
      if (gm < M) av = *reinterpret_cast<const float4*>(A + (size_t)gm * lda + k0 + kq);
      As[kq + 0][m] = av.x;
      As[kq + 1][m] = av.y;
      As[kq + 2][m] = av.z;
      As[kq + 3][m] = av.w;
    }
    #pragma unroll
    for (int i = tid; i < BK * BN / 4; i += 256) {
      const int kk = i / (BN / 4);
      const int n = (i % (BN / 4)) * 4;
      const int gn = n0 + n;
      float4 bv = make_float4(0.f, 0.f, 0.f, 0.f);
      if (gn < N) bv = *reinterpret_cast<const float4*>(B + (size_t)(k0 + kk) * ldb + gn);
      *reinterpret_cast<float4*>(&Bs[kk][n]) = bv;
    }
    __syncthreads();
    #pragma unroll
    for (int kk = 0; kk < BK; ++kk) {
      float a[TM], b[TN];
      #pragma unroll
      for (int i = 0; i < TM; ++i) a[i] = As[kk][ty * TM + i];
      #pragma unroll
      for (int j = 0; j < TN; ++j) b[j] = Bs[kk][tx * TN + j];
      #pragma unroll
      for (int i = 0; i < TM; ++i)
        #pragma unroll
        for (int j = 0; j < TN; ++j) acc[i][j] = fmaf(a[i], b[j], acc[i][j]);
    }
    __syncthreads();
  }
  #pragma unroll
  for (int i = 0; i < TM; ++i) {
    const int gm = m0 + ty * TM + i;
    if (gm >= M) continue;
    #pragma unroll
    for (int j = 0; j < TN; ++j) {
      const int gn = n0 + tx * TN + j;
      if (gn >= N) continue;
      float c = acc[i][j];
      if (bias) c += bias[gn];
      if (EPI == 1) c = phi_elu(c);
      else if (EPI == 2) c = gelu_exact(c);
      if (RES) c += Rp[(size_t)gm * ldr + gn];
      C[(size_t)gm * ldc + gn] = c;
    }
  }
}

// ---------------- Flash attention fp32 (causal + pad mask) ------------------
__global__ __launch_bounds__(256) void attn_kernel(
    const float* __restrict__ qkv, const int* __restrict__ amask,
    float* __restrict__ ctx) {
  const int tid = threadIdx.x, lane = tid & 63, wave = tid >> 6;
  const int bx = blockIdx.x, head = blockIdx.y, b = blockIdx.z;
  const int rq = bx * 4 + wave;
  __shared__ float ks[64][66], vs[64][66], qs[4][64], ps[4][64];
  const size_t qbase = ((size_t)b * SEQ) * (3 * H_DIM) + (size_t)head * HDm;
  qs[wave][lane] = qkv[qbase + (size_t)rq * (3 * H_DIM) + lane];
  float o = 0.f, m = -INFINITY, l = 0.f;
  const int ntiles = (bx * 4 + 3) / 64 + 1;
  for (int tile = 0; tile < ntiles; ++tile) {
    const int kb = tile * 64;
    __syncthreads();
    #pragma unroll
    for (int it = 0; it < 8; ++it) {
      const int idx = tid + it * 256;
      const int row = idx >> 5, c = (idx & 31) * 2;
      const float* gp = qkv + qbase + (size_t)(kb + row) * (3 * H_DIM) + H_DIM + c;
      const float2 kf = *reinterpret_cast<const float2*>(gp);
      const float2 vf = *reinterpret_cast<const float2*>(gp + H_DIM);
      ks[row][c] = kf.x; ks[row][c + 1] = kf.y;
      vs[row][c] = vf.x; vs[row][c + 1] = vf.y;
    }
    __syncthreads();
    float sc = 0.f;
    #pragma unroll
    for (int d = 0; d < 64; ++d) sc += qs[wave][d] * ks[lane][d];
    const int kg = kb + lane;
    const bool valid = (kg <= rq) && (amask[b * SEQ + kg] != 0);
    sc = valid ? sc * 0.125f : -INFINITY;
    const float mt = wave_max(sc);
    const float mn = fmaxf(m, mt);
    const float corr = __expf(m - mn);
    const float pj = valid ? __expf(sc - mn) : 0.f;
    const float lsum = wave_sum(pj);
    l = l * corr + lsum;
    o = o * corr;
    m = mn;
    ps[wave][lane] = pj;
    __syncthreads();
    #pragma unroll
    for (int j = 0; j < 64; ++j) o = fmaf(ps[wave][j], vs[j][lane], o);
  }
  ctx[((size_t)b * SEQ + rq) * H_DIM + head * HDm + lane] = o / l;
}

// ---------------- Fast-weights: banded Gram products ------------------------
// Gband[b][t][tau%256] = (kr_t . kr_tau) * (v_t . v_tau) for lag=t-tau in [0,256)
__global__ __launch_bounds__(256) void gram_kernel(
    const float* __restrict__ qkv, const float* __restrict__ kr,
    float* __restrict__ Gband) {
  __shared__ float As[16][68], Bs[16][68];
  const int b = blockIdx.z, t0 = blockIdx.y * 64;
  const int tau0 = t0 - BAND + blockIdx.x * 64;
  if (tau0 < 0) return;
  const int tid = threadIdx.x, tx = tid & 15, ty = tid >> 4;
  const float* vb = qkv + (size_t)b * SEQ * (3 * H_DIM) + 2 * H_DIM;
  const float* kb = kr + (size_t)b * SEQ * RDIM;
  float accV[4][4] = {{0.f}}, accK[4][4] = {{0.f}};
  const int m = tid >> 2, kq = (tid & 3) * 4;
  for (int chunk = 0; chunk < 68; ++chunk) {
    __syncthreads();
    if (chunk < 64) {
      const int k0 = chunk * 16;
      const float4 a4 = *reinterpret_cast<const float4*>(vb + (size_t)(t0 + m) * (3 * H_DIM) + k0 + kq);
      const float4 b4 = *reinterpret_cast<const float4*>(vb + (size_t)(tau0 + m) * (3 * H_DIM) + k0 + kq);
      As[kq + 0][m] = a4.x; As[kq + 1][m] = a4.y; As[kq + 2][m] = a4.z; As[kq + 3][m] = a4.w;
      Bs[kq + 0][m] = b4.x; Bs[kq + 1][m] = b4.y; Bs[kq + 2][m] = b4.z; Bs[kq + 3][m] = b4.w;
    } else {
      const int k0 = (chunk - 64) * 16;
      const float4 a4 = *reinterpret_cast<const float4*>(kb + (size_t)(t0 + m) * RDIM + k0 + kq);
      const float4 b4 = *reinterpret_cast<const float4*>(kb + (size_t)(tau0 + m) * RDIM + k0 + kq);
      As[kq + 0][m] = a4.x; As[kq + 1][m] = a4.y; As[kq + 2][m] = a4.z; As[kq + 3][m] = a4.w;
      Bs[kq + 0][m] = b4.x; Bs[kq + 1][m] = b4.y; Bs[kq + 2][m] = b4.z; Bs[kq + 3][m] = b4.w;
    }
    __syncthreads();
    #pragma unroll
    for (int kk = 0; kk < 16; ++kk) {
      float a[4], bb[4];
      #pragma unroll
      for (int i = 0; i < 4; ++i) a[i] = As[kk][ty * 4 + i];
      #pragma unroll
      for (int j = 0; j < 4; ++j) bb[j] = Bs[kk][tx * 4 + j];
      if (chunk < 64) {
        #pragma unroll
        for (int i = 0; i < 4; ++i)
          #pragma unroll
          for (int j = 0; j < 4; ++j) accV[i][j] = fmaf(a[i], bb[j], accV[i][j]);
      } else {
        #pragma unroll
        for (int i = 0; i < 4; ++i)
          #pragma unroll
          for (int j = 0; j < 4; ++j) accK[i][j] = fmaf(a[i], bb[j], accK[i][j]);
      }
    }
  }
  #pragma unroll
  for (int i = 0; i < 4; ++i) {
    const int t = t0 + ty * 4 + i;
    #pragma unroll
    for (int j = 0; j < 4; ++j) {
      const int tau = tau0 + tx * 4 + j;
      const int lag = t - tau;
      if (lag >= 0 && lag < BAND)
        Gband[((size_t)b * SEQ + t) * BAND + (tau & (BAND - 1))] = accK[i][j] * accV[i][j];
    }
  }
}

// ---------------- Fast-weights: scalar homeostatic scan ---------------------
__global__ __launch_bounds__(64) void fwscan_kernel(
    const float* __restrict__ Gband, float* __restrict__ L_arr) {
  const int b = blockIdx.x, lane = threadIdx.x;
  const float* grow = Gband + ((size_t)b * SEQ) * BAND + lane * 4;
  float u0 = 0.f, u1 = 0.f, u2 = 0.f, u3 = 0.f, n = 0.f, L = 0.f;
  float4 g0 = *reinterpret_cast<const float4*>(grow);
  float4 g1 = *reinterpret_cast<const float4*>(grow + BAND);
  for (int t = 0; t < SEQ; ++t) {
    float4 gn = make_float4(0.f, 0.f, 0.f, 0.f);
    if (t + 2 < SEQ) gn = *reinterpret_cast<const float4*>(grow + (size_t)(t + 2) * BAND);
    const int slot = t & (BAND - 1), owner = slot >> 2, elem = slot & 3;
    const float ge = (elem & 2) ? ((elem & 1) ? g0.w : g0.z) : ((elem & 1) ? g0.y : g0.x);
    const float gdiag = __shfl(ge, owner, 64);
    if (lane == owner) {           // expire slot (tau = t - 256, out of band)
      if (elem == 0) u0 = 0.f; else if (elem == 1) u1 = 0.f;
      else if (elem == 2) u2 = 0.f; else u3 = 0.f;
    }
    float cross = u0 * g0.x + u1 * g0.y + u2 * g0.z + u3 * g0.w;
    cross = wave_sum(cross);
    float np = GAMMA_C * GAMMA_C * n + 2.f * GAMMA_C * ALPHA_C * cross
             + ALPHA_C * ALPHA_C * gdiag;
    np = fmaxf(np, 0.f);
    const float s = 1.f / (1.f + BETA_C * sqrtf(np));
    n = s * s * np;
    const float gs = GAMMA_C * s, as = ALPHA_C * s;
    u0 *= gs; u1 *= gs; u2 *= gs; u3 *= gs;
    if (lane == owner) {           // insert tau = t
      if (elem == 0) u0 = as; else if (elem == 1) u1 = as;
      else if (elem == 2) u2 = as; else u3 = as;
    }
    L += logf(s);
    if (lane == 0) L_arr[b * SEQ + t] = L;
    g0 = g1; g1 = gn;
  }
}

// ---------------- Fast-weights: banded weighted attention y -----------------
__global__ __launch_bounds__(256) void fwy_kernel(
    const float* __restrict__ qkv, const float* __restrict__ qr,
    const float* __restrict__ kr, const float* __restrict__ L_arr,
    float* __restrict__ y) {
  __shared__ float qrT[64][68];
  __shared__ float kS[64][68];    // krT during S-phase, then w-tile (aliased)
  __shared__ float vs[64][64];
  const int b = blockIdx.z, t0 = blockIdx.y * 64, h0 = blockIdx.x * 64;
  const int tid = threadIdx.x, tx = tid & 15, ty = tid >> 4;
  const float* vbase = qkv + (size_t)b * SEQ * (3 * H_DIM) + 2 * H_DIM;
  const float* qrb = qr + (size_t)b * SEQ * RDIM;
  const float* krb = kr + (size_t)b * SEQ * RDIM;
  const float* Lb = L_arr + b * SEQ;
  #pragma unroll
  for (int it = 0; it < 4; ++it) {
    const int idx = tid + it * 256;
    const int i = idx >> 4, rq = (idx & 15) * 4;
    const float4 q4 = *reinterpret_cast<const float4*>(qrb + (size_t)(t0 + i) * RDIM + rq);
    qrT[rq + 0][i] = q4.x; qrT[rq + 1][i] = q4.y; qrT[rq + 2][i] = q4.z; qrT[rq + 3][i] = q4.w;
  }
  float Lt[4];
  #pragma unroll
  for (int mi = 0; mi < 4; ++mi) Lt[mi] = Lb[t0 + ty * 4 + mi];
  float acc[4][4];
  #pragma unroll
  for (int i = 0; i < 4; ++i)
    #pragma unroll
    for (int j = 0; j < 4; ++j) acc[i][j] = 0.f;

  for (int kt = 0; kt < 5; ++kt) {
    const int tau0 = t0 - BAND + kt * 64;
    if (tau0 < 0) continue;
    __syncthreads();
    #pragma unroll
    for (int it = 0; it < 4; ++it) {
      const int idx = tid + it * 256;
      const int j = idx >> 4, rq = (idx & 15) * 4;
      const float4 k4 = *reinterpret_cast<const float4*>(krb + (size_t)(tau0 + j) * RDIM + rq);
      kS[rq + 0][j] = k4.x; kS[rq + 1][j] = k4.y; kS[rq + 2][j] = k4.z; kS[rq + 3][j] = k4.w;
    }
    #pragma unroll
    for (int it = 0; it < 4; ++it) {
      const int idx = tid + it * 256;
      const int j = idx >> 4, hq = (idx & 15) * 4;
      *reinterpret_cast<float4*>(&vs[j][hq]) =
          *reinterpret_cast<const float4*>(vbase + (size_t)(tau0 + j) * (3 * H_DIM) + h0 + hq);
    }
    __syncthreads();
    float sacc[4][4];
    #pragma unroll
    for (int i = 0; i < 4; ++i)
      #pragma unroll
      for (int j = 0; j < 4; ++j) sacc[i][j] = 0.f;
    #pragma unroll 4
    for (int r = 0; r < 64; ++r) {
      float a[4], bb[4];
      #pragma unroll
      for (int i = 0; i < 4; ++i) a[i] = qrT[r][ty * 4 + i];
      #pragma unroll
      for (int j = 0; j < 4; ++j) bb[j] = kS[r][tx * 4 + j];
      #pragma unroll
      for (int i = 0; i < 4; ++i)
        #pragma unroll
        for (int j = 0; j < 4; ++j) sacc[i][j] = fmaf(a[i], bb[j], sacc[i][j]);
    }
    __syncthreads();
    #pragma unroll
    for (int mi = 0; mi < 4; ++mi) {
      const int t = t0 + ty * 4 + mi;
      #pragma unroll
      for (int nj = 0; nj < 4; ++nj) {
        const int tau = tau0 + tx * 4 + nj;
        const int lag = t - tau;
        float w = 0.f;
        if (lag >= 0 && lag < BAND) {
          const float Ltau = (tau > 0) ? Lb[tau - 1] : 0.f;
          w = ALPHA_C * __expf(fmaf((float)lag, LNGAMMA, Lt[mi] - Ltau)) * sacc[mi][nj];
        }
        kS[tx * 4 + nj][ty * 4 + mi] = w;
      }
    }
    __syncthreads();
    #pragma unroll 4
    for (int j = 0; j < 64; ++j) {
      float p[4], vv[4];
      #pragma unroll
      for (int mi = 0; mi < 4; ++mi) p[mi] = kS[j][ty * 4 + mi];
      #pragma unroll
      for (int nj = 0; nj < 4; ++nj) vv[nj] = vs[j][tx * 4 + nj];
      #pragma unroll
      for (int mi = 0; mi < 4; ++mi)
        #pragma unroll
        for (int nj = 0; nj < 4; ++nj) acc[mi][nj] = fmaf(p[mi], vv[nj], acc[mi][nj]);
    }
  }
  #pragma unroll
  for (int mi = 0; mi < 4; ++mi) {
    float4 o = make_float4(acc[mi][0], acc[mi][1], acc[mi][2], acc[mi][3]);
    *reinterpret_cast<float4*>(
        &y[((size_t)b * SEQ + t0 + ty * 4 + mi) * H_DIM + h0 + tx * 4]) = o;
  }
}

// ---------------- launch ----------------------------------------------------
extern "C" void kernel_launch(void* const* d_in, const int* in_sizes, int n_in,
                              void* d_out, int out_size, void* d_ws, size_t ws_size,
                              hipStream_t stream) {
  const float* x      = (const float*)d_in[0];
  const int*   amask  = (const int*)d_in[1];
  const float* ln1_g  = (const float*)d_in[2];
  const float* ln1_b  = (const float*)d_in[3];
  const float* qkv_w  = (const float*)d_in[4];
  const float* qkv_b  = (const float*)d_in[5];
  const float* out_w  = (const float*)d_in[6];
  const float* out_b  = (const float*)d_in[7];
  const float* fh_wq  = (const float*)d_in[8];
  const float* fh_wk  = (const float*)d_in[9];
  const float* fh_wo  = (const float*)d_in[10];
  const float* ln2_g  = (const float*)d_in[11];
  const float* ln2_b  = (const float*)d_in[12];
  const float* mlp_w1 = (const float*)d_in[13];
  const float* mlp_b1 = (const float*)d_in[14];
  const float* mlp_w2 = (const float*)d_in[15];
  const float* mlp_b2 = (const float*)d_in[16];
  float* out = (float*)d_out;
  float* ws  = (float*)d_ws;

  const int ROWS = BATCH * SEQ;  // 4096
  float* qkv = ws;                    // 12,582,912
  float* h1  = ws + 12582912;         // 4,194,304 (reused as ctx)
  float* ctx = h1;
  float* x1  = ws + 16777216;         // 4,194,304
  float* qr  = ws + 20971520;         // 262,144
  float* kr  = ws + 21233664;         // 262,144
  float* yy  = ws + 21495808;         // 4,194,304
  float* x2  = ws + 25690112;         // 4,194,304
  float* h2  = ws + 29884416;         // 4,194,304
  float* g1  = ws;                    // aliases dead qkv+h1 region at step 9
  float* Gband = h2;                  // 2*2048*256 = 1,048,576 (dead before LN2)
  float* L_arr = h2 + 1048576;        // 4096

  // 1) h1 = LN1(x)
  ln_kernel<<<ROWS, 256, 0, stream>>>(x, ln1_g, ln1_b, h1);
  // 2) qkv = h1 @ qkv_w + qkv_b                        [MFMA split-bf16]
  mgemm_kernel<0, false><<<dim3(3072 / 128, ROWS / 128), 256, 0, stream>>>(
      h1, H_DIM, qkv_w, 3 * H_DIM, qkv_b, nullptr, 0, qkv, 3 * H_DIM, ROWS, 3 * H_DIM, H_DIM);
  // 3) ctx = causal attention
  attn_kernel<<<dim3(SEQ / 4, NHEAD, BATCH), 256, 0, stream>>>(qkv, amask, ctx);
  // 4) x1 = x + ctx @ out_w + out_b                    [MFMA split-bf16]
  mgemm_kernel<0, true><<<dim3(1024 / 128, ROWS / 128), 256, 0, stream>>>(
      ctx, H_DIM, out_w, H_DIM, out_b, x, H_DIM, x1, H_DIM, ROWS, H_DIM, H_DIM);
  // 5) qr = phi(q @ fh_wq), kr = phi(k @ fh_wk)        [small: VALU path]
  gemm_kernel<128, 64, 16, 1, false><<<dim3(1, ROWS / 128), 256, 0, stream>>>(
      qkv, 3 * H_DIM, fh_wq, RDIM, nullptr, nullptr, 0, qr, RDIM, ROWS, RDIM, H_DIM);
  gemm_kernel<128, 64, 16, 1, false><<<dim3(1, ROWS / 128), 256, 0, stream>>>(
      qkv + H_DIM, 3 * H_DIM, fh_wk, RDIM, nullptr, nullptr, 0, kr, RDIM, ROWS, RDIM, H_DIM);
  // 6) banded Gram products, scalar homeostatic scan, weighted-attention y
  gram_kernel<<<dim3(5, SEQ / 64, BATCH), 256, 0, stream>>>(qkv, kr, Gband);
  fwscan_kernel<<<BATCH, 64, 0, stream>>>(Gband, L_arr);
  fwy_kernel<<<dim3(H_DIM / 64, SEQ / 64, BATCH), 256, 0, stream>>>(qkv, qr, kr, L_arr, yy);
  // 7) x2 = x1 + yy @ fh_wo                            [MFMA split-bf16]
  mgemm_kernel<0, true><<<dim3(1024 / 128, ROWS / 128), 256, 0, stream>>>(
      yy, H_DIM, fh_wo, H_DIM, nullptr, x1, H_DIM, x2, H_DIM, ROWS, H_DIM, H_DIM);
  // 8) h2 = LN2(x2)
  ln_kernel<<<ROWS, 256, 0, stream>>>(x2, ln2_g, ln2_b, h2);
  // 9) g1 = gelu(h2 @ mlp_w1 + mlp_b1)                 [MFMA split-bf16]
  mgemm_kernel<2, false><<<dim3(4096 / 128, ROWS / 128), 256, 0, stream>>>(
      h2, H_DIM, mlp_w1, MDIM, mlp_b1, nullptr, 0, g1, MDIM, ROWS, MDIM, H_DIM);
  // 10) out = x2 + g1 @ mlp_w2 + mlp_b2                [MFMA split-bf16]
  mgemm_kernel<0, true><<<dim3(1024 / 128, ROWS / 128), 256, 0, stream>>>(
      g1, MDIM, mlp_w2, H_DIM, mlp_b2, x2, H_DIM, out, H_DIM, ROWS, H_DIM, MDIM);
}

// Round 6
// 2758.657 us; speedup vs baseline: 3.3997x; 1.3702x over previous
//
#include <hip/hip_runtime.h>
#include <hip/hip_bf16.h>
#include <math.h>

// Problem constants (match reference)
#define H_DIM 1024
#define NHEAD 16
#define HDm   64
#define SEQ   2048
#define BATCH 2
#define RDIM  64
#define MDIM  4096
#define ALPHA_C 0.5f
#define BETA_C  0.1f
#define GAMMA_C 0.95f
#define LNGAMMA (-0.051293294387550533f)
#define BAND 256

typedef __attribute__((ext_vector_type(8))) short bfrag;   // 8 bf16 (4 VGPRs)
typedef __attribute__((ext_vector_type(4))) float facc;    // 4 fp32

__device__ __forceinline__ float gelu_exact(float x) {
  return 0.5f * x * (1.f + erff(x * 0.70710678118654752f));
}
__device__ __forceinline__ float phi_elu(float x) {   // elu(x)+1
  return x > 0.f ? x + 1.f : __expf(x);
}
__device__ __forceinline__ float wave_sum(float v) {
  #pragma unroll
  for (int o = 32; o > 0; o >>= 1) v += __shfl_xor(v, o, 64);
  return v;
}
__device__ __forceinline__ unsigned short f2bf(float f) {   // RNE fp32->bf16
  unsigned int u = __float_as_uint(f);
  u += 0x7fffu + ((u >> 16) & 1u);
  return (unsigned short)(u >> 16);
}
__device__ __forceinline__ float bf2f(unsigned short s) {
  return __uint_as_float(((unsigned int)s) << 16);
}

// ---------------- LayerNorm: one block per row (H=1024, 256 thr x float4) ----
__global__ __launch_bounds__(256) void ln_kernel(
    const float* __restrict__ x, const float* __restrict__ g,
    const float* __restrict__ bt, float* __restrict__ out) {
  __shared__ float lds[4];
  const int row = blockIdx.x;
  const int tid = threadIdx.x;
  const float4 v = reinterpret_cast<const float4*>(x + (size_t)row * H_DIM)[tid];
  float s = (v.x + v.y) + (v.z + v.w);
  s = wave_sum(s);
  if ((tid & 63) == 0) lds[tid >> 6] = s;
  __syncthreads();
  const float mu = (lds[0] + lds[1] + lds[2] + lds[3]) * (1.f / H_DIM);
  __syncthreads();
  float4 d;
  d.x = v.x - mu; d.y = v.y - mu; d.z = v.z - mu; d.w = v.w - mu;
  float s2 = (d.x * d.x + d.y * d.y) + (d.z * d.z + d.w * d.w);
  s2 = wave_sum(s2);
  if ((tid & 63) == 0) lds[tid >> 6] = s2;
  __syncthreads();
  const float var = (lds[0] + lds[1] + lds[2] + lds[3]) * (1.f / H_DIM);
  const float rs = rsqrtf(var + 1e-5f);
  const float4 gg = reinterpret_cast<const float4*>(g)[tid];
  const float4 bb = reinterpret_cast<const float4*>(bt)[tid];
  float4 o;
  o.x = d.x * rs * gg.x + bb.x;
  o.y = d.y * rs * gg.y + bb.y;
  o.z = d.z * rs * gg.z + bb.z;
  o.w = d.w * rs * gg.w + bb.w;
  reinterpret_cast<float4*>(out + (size_t)row * H_DIM)[tid] = o;
}

// ---------------- Split-bf16 MFMA GEMM: C = act(A@B + bias) + R -------------
// fp32 in/out; hi/lo bf16 split; 3 MFMA per product (~2^-17 rel err).
// 128x128 tile, BK=32, 256 thr = 4 waves 2x2, wave = 64x64 via 4x4 16x16x32.
// C/D layout (HW-verified): col = lane&15, row = (lane>>4)*4 + reg.
#define LP 40   // LDS row pitch in ushorts (32 used + 8 pad -> 80B rows)
template <int EPI, bool RES>
__global__ __launch_bounds__(256) void mgemm_kernel(
    const float* __restrict__ A, int lda,
    const float* __restrict__ B, int ldb,
    const float* __restrict__ bias,
    const float* __restrict__ Rp, int ldr,
    float* __restrict__ C, int ldc,
    int M, int N, int K) {
  __shared__ unsigned short Ah[128 * LP], Al[128 * LP];
  __shared__ unsigned short Bh[128 * LP], Bl[128 * LP];
  const int tid = threadIdx.x;
  const int lane = tid & 63, wv = tid >> 6;
  const int wr = wv >> 1, wc = wv & 1;
  const int g = lane >> 4, lr = lane & 15;
  const int m0 = blockIdx.y * 128, n0 = blockIdx.x * 128;
  facc acc[4][4];
  #pragma unroll
  for (int i = 0; i < 4; ++i)
    #pragma unroll
    for (int j = 0; j < 4; ++j) acc[i][j] = (facc)(0.f);

  for (int k0 = 0; k0 < K; k0 += 32) {
    __syncthreads();
    #pragma unroll
    for (int it = 0; it < 4; ++it) {
      const int i = tid + it * 256;
      const int m = i >> 3, q = i & 7;
      const float4 a4 = *reinterpret_cast<const float4*>(
          A + (size_t)(m0 + m) * lda + k0 + q * 4);
      ushort4 hi, lo;
      hi.x = f2bf(a4.x); lo.x = f2bf(a4.x - bf2f(hi.x));
      hi.y = f2bf(a4.y); lo.y = f2bf(a4.y - bf2f(hi.y));
      hi.z = f2bf(a4.z); lo.z = f2bf(a4.z - bf2f(hi.z));
      hi.w = f2bf(a4.w); lo.w = f2bf(a4.w - bf2f(hi.w));
      *reinterpret_cast<ushort4*>(&Ah[m * LP + q * 4]) = hi;
      *reinterpret_cast<ushort4*>(&Al[m * LP + q * 4]) = lo;
    }
    #pragma unroll
    for (int it = 0; it < 4; ++it) {
      const int i = tid + it * 256;
      const int n = i & 127, kc = (i >> 7) * 4;
      const float* bp = B + (size_t)(k0 + kc) * ldb + n0 + n;
      const float b0 = bp[0];
      const float b1 = bp[(size_t)ldb];
      const float b2 = bp[(size_t)2 * ldb];
      const float b3 = bp[(size_t)3 * ldb];
      ushort4 hi, lo;
      hi.x = f2bf(b0); lo.x = f2bf(b0 - bf2f(hi.x));
      hi.y = f2bf(b1); lo.y = f2bf(b1 - bf2f(hi.y));
      hi.z = f2bf(b2); lo.z = f2bf(b2 - bf2f(hi.z));
      hi.w = f2bf(b3); lo.w = f2bf(b3 - bf2f(hi.w));
      *reinterpret_cast<ushort4*>(&Bh[n * LP + kc]) = hi;
      *reinterpret_cast<ushort4*>(&Bl[n * LP + kc]) = lo;
    }
    __syncthreads();
    bfrag ah[4], al[4], bh[4], bl[4];
    #pragma unroll
    for (int mi = 0; mi < 4; ++mi) {
      const int r = wr * 64 + mi * 16 + lr;
      ah[mi] = *reinterpret_cast<const bfrag*>(&Ah[r * LP + g * 8]);
      al[mi] = *reinterpret_cast<const bfrag*>(&Al[r * LP + g * 8]);
    }
    #pragma unroll
    for (int nj = 0; nj < 4; ++nj) {
      const int c = wc * 64 + nj * 16 + lr;
      bh[nj] = *reinterpret_cast<const bfrag*>(&Bh[c * LP + g * 8]);
      bl[nj] = *reinterpret_cast<const bfrag*>(&Bl[c * LP + g * 8]);
    }
    #pragma unroll
    for (int mi = 0; mi < 4; ++mi)
      #pragma unroll
      for (int nj = 0; nj < 4; ++nj) {
        acc[mi][nj] = __builtin_amdgcn_mfma_f32_16x16x32_bf16(
            ah[mi], bh[nj], acc[mi][nj], 0, 0, 0);
        acc[mi][nj] = __builtin_amdgcn_mfma_f32_16x16x32_bf16(
            ah[mi], bl[nj], acc[mi][nj], 0, 0, 0);
        acc[mi][nj] = __builtin_amdgcn_mfma_f32_16x16x32_bf16(
            al[mi], bh[nj], acc[mi][nj], 0, 0, 0);
      }
  }
  #pragma unroll
  for (int mi = 0; mi < 4; ++mi) {
    const int row0 = m0 + wr * 64 + mi * 16 + g * 4;
    #pragma unroll
    for (int nj = 0; nj < 4; ++nj) {
      const int col = n0 + wc * 64 + nj * 16 + lr;
      const float bs = bias ? bias[col] : 0.f;
      #pragma unroll
      for (int r = 0; r < 4; ++r) {
        float cv = acc[mi][nj][r] + bs;
        if (EPI == 1) cv = phi_elu(cv);
        else if (EPI == 2) cv = gelu_exact(cv);
        if (RES) cv += Rp[(size_t)(row0 + r) * ldr + col];
        C[(size_t)(row0 + r) * ldc + col] = cv;
      }
    }
  }
}

// ---------------- Generic fp32 tiled GEMM (small shapes: qr/kr) ------------
template <int BM, int BN, int BK, int EPI, bool RES>
__global__ __launch_bounds__(256) void gemm_kernel(
    const float* __restrict__ A, int lda,
    const float* __restrict__ B, int ldb,
    const float* __restrict__ bias,
    const float* __restrict__ Rp, int ldr,
    float* __restrict__ C, int ldc,
    int M, int N, int K) {
  constexpr int TM = BM / 16, TN = BN / 16;
  __shared__ float As[BK][BM + 4];
  __shared__ float Bs[BK][BN + 4];
  const int tid = threadIdx.x;
  const int tx = tid & 15, ty = tid >> 4;
  const int m0 = blockIdx.y * BM, n0 = blockIdx.x * BN;
  float acc[TM][TN];
  #pragma unroll
  for (int i = 0; i < TM; ++i)
    #pragma unroll
    for (int j = 0; j < TN; ++j) acc[i][j] = 0.f;

  for (int k0 = 0; k0 < K; k0 += BK) {
    #pragma unroll
    for (int i = tid; i < BM * BK / 4; i += 256) {
      const int m = i / (BK / 4);
      const int kq = (i % (BK / 4)) * 4;
      const int gm = m0 + m;
      float4 av = make_float4(0.f, 0.f, 0.f, 0.f);
      if (gm < M) av = *reinterpret_cast<const float4*>(A + (size_t)gm * lda + k0 + kq);
      As[kq + 0][m] = av.x;
      As[kq + 1][m] = av.y;
      As[kq + 2][m] = av.z;
      As[kq + 3][m] = av.w;
    }
    #pragma unroll
    for (int i = tid; i < BK * BN / 4; i += 256) {
      const int kk = i / (BN / 4);
      const int n = (i % (BN / 4)) * 4;
      const int gn = n0 + n;
      float4 bv = make_float4(0.f, 0.f, 0.f, 0.f);
      if (gn < N) bv = *reinterpret_cast<const float4*>(B + (size_t)(k0 + kk) * ldb + gn);
      *reinterpret_cast<float4*>(&Bs[kk][n]) = bv;
    }
    __syncthreads();
    #pragma unroll
    for (int kk = 0; kk < BK; ++kk) {
      float a[TM], b[TN];
      #pragma unroll
      for (int i = 0; i < TM; ++i) a[i] = As[kk][ty * TM + i];
      #pragma unroll
      for (int j = 0; j < TN; ++j) b[j] = Bs[kk][tx * TN + j];
      #pragma unroll
      for (int i = 0; i < TM; ++i)
        #pragma unroll
        for (int j = 0; j < TN; ++j) acc[i][j] = fmaf(a[i], b[j], acc[i][j]);
    }
    __syncthreads();
  }
  #pragma unroll
  for (int i = 0; i < TM; ++i) {
    const int gm = m0 + ty * TM + i;
    if (gm >= M) continue;
    #pragma unroll
    for (int j = 0; j < TN; ++j) {
      const int gn = n0 + tx * TN + j;
      if (gn >= N) continue;
      float c = acc[i][j];
      if (bias) c += bias[gn];
      if (EPI == 1) c = phi_elu(c);
      else if (EPI == 2) c = gelu_exact(c);
      if (RES) c += Rp[(size_t)gm * ldr + gn];
      C[(size_t)gm * ldc + gn] = c;
    }
  }
}

// ---------------- K/V fp32 -> split-bf16 pre-pass ---------------------------
// kvh/kvl: [B*S][2048] ushorts; cols 0..1023 = K, 1024..2047 = V.
__global__ __launch_bounds__(256) void kvconv_kernel(
    const float* __restrict__ qkv, unsigned short* __restrict__ kvh,
    unsigned short* __restrict__ kvl) {
  const size_t i = (size_t)blockIdx.x * 256 + threadIdx.x;  // quad index
  const int row = (int)(i >> 9);             // 512 quads per row
  const int cq = ((int)i & 511) * 4;
  const float4 v = *reinterpret_cast<const float4*>(
      qkv + (size_t)row * (3 * H_DIM) + H_DIM + cq);
  ushort4 hi, lo;
  hi.x = f2bf(v.x); lo.x = f2bf(v.x - bf2f(hi.x));
  hi.y = f2bf(v.y); lo.y = f2bf(v.y - bf2f(hi.y));
  hi.z = f2bf(v.z); lo.z = f2bf(v.z - bf2f(hi.z));
  hi.w = f2bf(v.w); lo.w = f2bf(v.w - bf2f(hi.w));
  *reinterpret_cast<ushort4*>(kvh + (size_t)row * 2048 + cq) = hi;
  *reinterpret_cast<ushort4*>(kvl + (size_t)row * 2048 + cq) = lo;
}

// ---------------- Split-bf16 MFMA flash attention ---------------------------
// grid (SEQ/64, NHEAD, BATCH), 256 thr = 4 waves; wave owns 16 q-rows.
// QK^T and PV each via 3-MFMA split-bf16 (fp32-equivalent numerics).
// D-layout: row=(lane>>4)*4+reg, col=lane&15. A-frag: row=lane&15, k=g*8+j.
#define KP 72   // LDS pitch in ushorts (144B, 16B-aligned, odd multiple of 4)
__global__ __launch_bounds__(256) void attn_mfma_kernel(
    const float* __restrict__ qkv, const unsigned short* __restrict__ kvh,
    const unsigned short* __restrict__ kvl, const int* __restrict__ amask,
    float* __restrict__ ctx) {
  __shared__ unsigned short Kh[64 * KP], Kl[64 * KP];   // [key][d]
  __shared__ unsigned short Vh[64 * KP], Vl[64 * KP];   // [d][key] (transposed)
  __shared__ unsigned short Ph[4][16 * KP], Pl[4][16 * KP];
  const int tid = threadIdx.x, lane = tid & 63, w = tid >> 6;
  const int g = lane >> 4, lr = lane & 15;
  const int qb = blockIdx.x, head = blockIdx.y, b = blockIdx.z;
  const int t0 = qb * 64;
  // Q A-frags direct from global fp32 (row = lane&15 within wave's 16 rows)
  const int qrow = t0 + w * 16 + lr;
  const float* qp = qkv + ((size_t)b * SEQ + qrow) * (3 * H_DIM) + head * HDm;
  bfrag qh[2], ql[2];
  #pragma unroll
  for (int ks = 0; ks < 2; ++ks) {
    float qv[8];
    *reinterpret_cast<float4*>(&qv[0]) =
        *reinterpret_cast<const float4*>(qp + ks * 32 + g * 8);
    *reinterpret_cast<float4*>(&qv[4]) =
        *reinterpret_cast<const float4*>(qp + ks * 32 + g * 8 + 4);
    #pragma unroll
    for (int j = 0; j < 8; ++j) {
      const unsigned short h = f2bf(qv[j]);
      qh[ks][j] = (short)h;
      ql[ks][j] = (short)f2bf(qv[j] - bf2f(h));
    }
  }
  // online-softmax state: rows 4g+reg (per D-layout)
  float mrow[4] = {-1e30f, -1e30f, -1e30f, -1e30f};
  float lrow[4] = {0.f, 0.f, 0.f, 0.f};
  facc oacc[4];
  #pragma unroll
  for (int nf = 0; nf < 4; ++nf) oacc[nf] = (facc)(0.f);

  for (int kt = 0; kt <= qb; ++kt) {
    const int kb = kt * 64;
    __syncthreads();
    // stage K [key][d] and V [d][key] tiles from pre-converted bf16
    #pragma unroll
    for (int it = 0; it < 4; ++it) {
      const int qid = tid + it * 256;
      const int key = qid >> 4, d0 = (qid & 15) * 4;
      const size_t gb = ((size_t)b * SEQ + kb + key) * 2048 + head * HDm + d0;
      const ushort4 kh4 = *reinterpret_cast<const ushort4*>(kvh + gb);
      const ushort4 kl4 = *reinterpret_cast<const ushort4*>(kvl + gb);
      *reinterpret_cast<ushort4*>(&Kh[key * KP + d0]) = kh4;
      *reinterpret_cast<ushort4*>(&Kl[key * KP + d0]) = kl4;
      const ushort4 vh4 = *reinterpret_cast<const ushort4*>(kvh + gb + H_DIM);
      const ushort4 vl4 = *reinterpret_cast<const ushort4*>(kvl + gb + H_DIM);
      Vh[(d0 + 0) * KP + key] = vh4.x; Vh[(d0 + 1) * KP + key] = vh4.y;
      Vh[(d0 + 2) * KP + key] = vh4.z; Vh[(d0 + 3) * KP + key] = vh4.w;
      Vl[(d0 + 0) * KP + key] = vl4.x; Vl[(d0 + 1) * KP + key] = vl4.y;
      Vl[(d0 + 2) * KP + key] = vl4.z; Vl[(d0 + 3) * KP + key] = vl4.w;
    }
    __syncthreads();
    // S = Q K^T (cols = keys)
    facc sacc[4];
    #pragma unroll
    for (int nf = 0; nf < 4; ++nf) sacc[nf] = (facc)(0.f);
    #pragma unroll
    for (int ks = 0; ks < 2; ++ks) {
      #pragma unroll
      for (int nf = 0; nf < 4; ++nf) {
        const bfrag kbh = *reinterpret_cast<const bfrag*>(
            &Kh[(nf * 16 + lr) * KP + ks * 32 + g * 8]);
        const bfrag kbl = *reinterpret_cast<const bfrag*>(
            &Kl[(nf * 16 + lr) * KP + ks * 32 + g * 8]);
        sacc[nf] = __builtin_amdgcn_mfma_f32_16x16x32_bf16(qh[ks], kbh, sacc[nf], 0, 0, 0);
        sacc[nf] = __builtin_amdgcn_mfma_f32_16x16x32_bf16(qh[ks], kbl, sacc[nf], 0, 0, 0);
        sacc[nf] = __builtin_amdgcn_mfma_f32_16x16x32_bf16(ql[ks], kbh, sacc[nf], 0, 0, 0);
      }
    }
    // online softmax over this tile
    float sval[4][4], tmax[4] = {-1e30f, -1e30f, -1e30f, -1e30f};
    #pragma unroll
    for (int nf = 0; nf < 4; ++nf) {
      const int key = kb + nf * 16 + lr;
      const bool am = amask[b * SEQ + key] != 0;
      #pragma unroll
      for (int r = 0; r < 4; ++r) {
        const int rq = t0 + w * 16 + g * 4 + r;
        float s = sacc[nf][r] * 0.125f;
        s = (am && key <= rq) ? s : -1e30f;
        sval[nf][r] = s;
        tmax[r] = fmaxf(tmax[r], s);
      }
    }
    #pragma unroll
    for (int o = 1; o < 16; o <<= 1)
      #pragma unroll
      for (int r = 0; r < 4; ++r) tmax[r] = fmaxf(tmax[r], __shfl_xor(tmax[r], o, 64));
    float corr[4], lsum[4] = {0.f, 0.f, 0.f, 0.f};
    #pragma unroll
    for (int r = 0; r < 4; ++r) {
      const float mn = fmaxf(mrow[r], tmax[r]);
      corr[r] = __expf(mrow[r] - mn);
      mrow[r] = mn;
    }
    #pragma unroll
    for (int nf = 0; nf < 4; ++nf)
      #pragma unroll
      for (int r = 0; r < 4; ++r) {
        const float p = (sval[nf][r] > -0.9e30f) ? __expf(sval[nf][r] - mrow[r]) : 0.f;
        lsum[r] += p;
        const unsigned short ph = f2bf(p);
        Ph[w][(g * 4 + r) * KP + nf * 16 + lr] = ph;
        Pl[w][(g * 4 + r) * KP + nf * 16 + lr] = f2bf(p - bf2f(ph));
      }
    #pragma unroll
    for (int o = 1; o < 16; o <<= 1)
      #pragma unroll
      for (int r = 0; r < 4; ++r) lsum[r] += __shfl_xor(lsum[r], o, 64);
    #pragma unroll
    for (int r = 0; r < 4; ++r) lrow[r] = lrow[r] * corr[r] + lsum[r];
    #pragma unroll
    for (int nf = 0; nf < 4; ++nf)
      #pragma unroll
      for (int r = 0; r < 4; ++r) oacc[nf][r] *= corr[r];
    // O += P V  (P per-wave in LDS; same-wave write->read ordering via lgkmcnt)
    #pragma unroll
    for (int ks = 0; ks < 2; ++ks) {
      const bfrag pah = *reinterpret_cast<const bfrag*>(&Ph[w][lr * KP + ks * 32 + g * 8]);
      const bfrag pal = *reinterpret_cast<const bfrag*>(&Pl[w][lr * KP + ks * 32 + g * 8]);
      #pragma unroll
      for (int nf = 0; nf < 4; ++nf) {
        const bfrag vbh = *reinterpret_cast<const bfrag*>(
            &Vh[(nf * 16 + lr) * KP + ks * 32 + g * 8]);
        const bfrag vbl = *reinterpret_cast<const bfrag*>(
            &Vl[(nf * 16 + lr) * KP + ks * 32 + g * 8]);
        oacc[nf] = __builtin_amdgcn_mfma_f32_16x16x32_bf16(pah, vbh, oacc[nf], 0, 0, 0);
        oacc[nf] = __builtin_amdgcn_mfma_f32_16x16x32_bf16(pah, vbl, oacc[nf], 0, 0, 0);
        oacc[nf] = __builtin_amdgcn_mfma_f32_16x16x32_bf16(pal, vbh, oacc[nf], 0, 0, 0);
      }
    }
  }
  float* op = ctx + ((size_t)b * SEQ + t0 + w * 16) * H_DIM + head * HDm;
  #pragma unroll
  for (int nf = 0; nf < 4; ++nf)
    #pragma unroll
    for (int r = 0; r < 4; ++r)
      op[(size_t)(g * 4 + r) * H_DIM + nf * 16 + lr] =
          oacc[nf][r] / fmaxf(lrow[r], 1e-30f);
}

// ---------------- Fast-weights: banded Gram products ------------------------
__global__ __launch_bounds__(256) void gram_kernel(
    const float* __restrict__ qkv, const float* __restrict__ kr,
    float* __restrict__ Gband) {
  __shared__ float As[16][68], Bs[16][68];
  const int b = blockIdx.z, t0 = blockIdx.y * 64;
  const int tau0 = t0 - BAND + blockIdx.x * 64;
  if (tau0 < 0) return;
  const int tid = threadIdx.x, tx = tid & 15, ty = tid >> 4;
  const float* vb = qkv + (size_t)b * SEQ * (3 * H_DIM) + 2 * H_DIM;
  const float* kb = kr + (size_t)b * SEQ * RDIM;
  float accV[4][4] = {{0.f}}, accK[4][4] = {{0.f}};
  const int m = tid >> 2, kq = (tid & 3) * 4;
  for (int chunk = 0; chunk < 68; ++chunk) {
    __syncthreads();
    if (chunk < 64) {
      const int k0 = chunk * 16;
      const float4 a4 = *reinterpret_cast<const float4*>(vb + (size_t)(t0 + m) * (3 * H_DIM) + k0 + kq);
      const float4 b4 = *reinterpret_cast<const float4*>(vb + (size_t)(tau0 + m) * (3 * H_DIM) + k0 + kq);
      As[kq + 0][m] = a4.x; As[kq + 1][m] = a4.y; As[kq + 2][m] = a4.z; As[kq + 3][m] = a4.w;
      Bs[kq + 0][m] = b4.x; Bs[kq + 1][m] = b4.y; Bs[kq + 2][m] = b4.z; Bs[kq + 3][m] = b4.w;
    } else {
      const int k0 = (chunk - 64) * 16;
      const float4 a4 = *reinterpret_cast<const float4*>(kb + (size_t)(t0 + m) * RDIM + k0 + kq);
      const float4 b4 = *reinterpret_cast<const float4*>(kb + (size_t)(tau0 + m) * RDIM + k0 + kq);
      As[kq + 0][m] = a4.x; As[kq + 1][m] = a4.y; As[kq + 2][m] = a4.z; As[kq + 3][m] = a4.w;
      Bs[kq + 0][m] = b4.x; Bs[kq + 1][m] = b4.y; Bs[kq + 2][m] = b4.z; Bs[kq + 3][m] = b4.w;
    }
    __syncthreads();
    #pragma unroll
    for (int kk = 0; kk < 16; ++kk) {
      float a[4], bb[4];
      #pragma unroll
      for (int i = 0; i < 4; ++i) a[i] = As[kk][ty * 4 + i];
      #pragma unroll
      for (int j = 0; j < 4; ++j) bb[j] = Bs[kk][tx * 4 + j];
      if (chunk < 64) {
        #pragma unroll
        for (int i = 0; i < 4; ++i)
          #pragma unroll
          for (int j = 0; j < 4; ++j) accV[i][j] = fmaf(a[i], bb[j], accV[i][j]);
      } else {
        #pragma unroll
        for (int i = 0; i < 4; ++i)
          #pragma unroll
          for (int j = 0; j < 4; ++j) accK[i][j] = fmaf(a[i], bb[j], accK[i][j]);
      }
    }
  }
  #pragma unroll
  for (int i = 0; i < 4; ++i) {
    const int t = t0 + ty * 4 + i;
    #pragma unroll
    for (int j = 0; j < 4; ++j) {
      const int tau = tau0 + tx * 4 + j;
      const int lag = t - tau;
      if (lag >= 0 && lag < BAND)
        Gband[((size_t)b * SEQ + t) * BAND + (tau & (BAND - 1))] = accK[i][j] * accV[i][j];
    }
  }
}

// ---------------- Fast-weights: scalar homeostatic scan ---------------------
__global__ __launch_bounds__(64) void fwscan_kernel(
    const float* __restrict__ Gband, float* __restrict__ L_arr) {
  const int b = blockIdx.x, lane = threadIdx.x;
  const float* grow = Gband + ((size_t)b * SEQ) * BAND + lane * 4;
  float u0 = 0.f, u1 = 0.f, u2 = 0.f, u3 = 0.f, n = 0.f, L = 0.f;
  float4 g0 = *reinterpret_cast<const float4*>(grow);
  float4 g1 = *reinterpret_cast<const float4*>(grow + BAND);
  for (int t = 0; t < SEQ; ++t) {
    float4 gn = make_float4(0.f, 0.f, 0.f, 0.f);
    if (t + 2 < SEQ) gn = *reinterpret_cast<const float4*>(grow + (size_t)(t + 2) * BAND);
    const int slot = t & (BAND - 1), owner = slot >> 2, elem = slot & 3;
    const float ge = (elem & 2) ? ((elem & 1) ? g0.w : g0.z) : ((elem & 1) ? g0.y : g0.x);
    const float gdiag = __shfl(ge, owner, 64);
    if (lane == owner) {
      if (elem == 0) u0 = 0.f; else if (elem == 1) u1 = 0.f;
      else if (elem == 2) u2 = 0.f; else u3 = 0.f;
    }
    float cross = u0 * g0.x + u1 * g0.y + u2 * g0.z + u3 * g0.w;
    cross = wave_sum(cross);
    float np = GAMMA_C * GAMMA_C * n + 2.f * GAMMA_C * ALPHA_C * cross
             + ALPHA_C * ALPHA_C * gdiag;
    np = fmaxf(np, 0.f);
    const float s = 1.f / (1.f + BETA_C * sqrtf(np));
    n = s * s * np;
    const float gs = GAMMA_C * s, as = ALPHA_C * s;
    u0 *= gs; u1 *= gs; u2 *= gs; u3 *= gs;
    if (lane == owner) {
      if (elem == 0) u0 = as; else if (elem == 1) u1 = as;
      else if (elem == 2) u2 = as; else u3 = as;
    }
    L += logf(s);
    if (lane == 0) L_arr[b * SEQ + t] = L;
    g0 = g1; g1 = gn;
  }
}

// ---------------- Fast-weights: banded weighted attention y -----------------
__global__ __launch_bounds__(256) void fwy_kernel(
    const float* __restrict__ qkv, const float* __restrict__ qr,
    const float* __restrict__ kr, const float* __restrict__ L_arr,
    float* __restrict__ y) {
  __shared__ float qrT[64][68];
  __shared__ float kS[64][68];
  __shared__ float vs[64][64];
  const int b = blockIdx.z, t0 = blockIdx.y * 64, h0 = blockIdx.x * 64;
  const int tid = threadIdx.x, tx = tid & 15, ty = tid >> 4;
  const float* vbase = qkv + (size_t)b * SEQ * (3 * H_DIM) + 2 * H_DIM;
  const float* qrb = qr + (size_t)b * SEQ * RDIM;
  const float* krb = kr + (size_t)b * SEQ * RDIM;
  const float* Lb = L_arr + b * SEQ;
  #pragma unroll
  for (int it = 0; it < 4; ++it) {
    const int idx = tid + it * 256;
    const int i = idx >> 4, rq = (idx & 15) * 4;
    const float4 q4 = *reinterpret_cast<const float4*>(qrb + (size_t)(t0 + i) * RDIM + rq);
    qrT[rq + 0][i] = q4.x; qrT[rq + 1][i] = q4.y; qrT[rq + 2][i] = q4.z; qrT[rq + 3][i] = q4.w;
  }
  float Lt[4];
  #pragma unroll
  for (int mi = 0; mi < 4; ++mi) Lt[mi] = Lb[t0 + ty * 4 + mi];
  float acc[4][4];
  #pragma unroll
  for (int i = 0; i < 4; ++i)
    #pragma unroll
    for (int j = 0; j < 4; ++j) acc[i][j] = 0.f;

  for (int kt = 0; kt < 5; ++kt) {
    const int tau0 = t0 - BAND + kt * 64;
    if (tau0 < 0) continue;
    __syncthreads();
    #pragma unroll
    for (int it = 0; it < 4; ++it) {
      const int idx = tid + it * 256;
      const int j = idx >> 4, rq = (idx & 15) * 4;
      const float4 k4 = *reinterpret_cast<const float4*>(krb + (size_t)(tau0 + j) * RDIM + rq);
      kS[rq + 0][j] = k4.x; kS[rq + 1][j] = k4.y; kS[rq + 2][j] = k4.z; kS[rq + 3][j] = k4.w;
    }
    #pragma unroll
    for (int it = 0; it < 4; ++it) {
      const int idx = tid + it * 256;
      const int j = idx >> 4, hq = (idx & 15) * 4;
      *reinterpret_cast<float4*>(&vs[j][hq]) =
          *reinterpret_cast<const float4*>(vbase + (size_t)(tau0 + j) * (3 * H_DIM) + h0 + hq);
    }
    __syncthreads();
    float sacc[4][4];
    #pragma unroll
    for (int i = 0; i < 4; ++i)
      #pragma unroll
      for (int j = 0; j < 4; ++j) sacc[i][j] = 0.f;
    #pragma unroll 4
    for (int r = 0; r < 64; ++r) {
      float a[4], bb[4];
      #pragma unroll
      for (int i = 0; i < 4; ++i) a[i] = qrT[r][ty * 4 + i];
      #pragma unroll
      for (int j = 0; j < 4; ++j) bb[j] = kS[r][tx * 4 + j];
      #pragma unroll
      for (int i = 0; i < 4; ++i)
        #pragma unroll
        for (int j = 0; j < 4; ++j) sacc[i][j] = fmaf(a[i], bb[j], sacc[i][j]);
    }
    __syncthreads();
    #pragma unroll
    for (int mi = 0; mi < 4; ++mi) {
      const int t = t0 + ty * 4 + mi;
      #pragma unroll
      for (int nj = 0; nj < 4; ++nj) {
        const int tau = tau0 + tx * 4 + nj;
        const int lag = t - tau;
        float w = 0.f;
        if (lag >= 0 && lag < BAND) {
          const float Ltau = (tau > 0) ? Lb[tau - 1] : 0.f;
          w = ALPHA_C * __expf(fmaf((float)lag, LNGAMMA, Lt[mi] - Ltau)) * sacc[mi][nj];
        }
        kS[tx * 4 + nj][ty * 4 + mi] = w;
      }
    }
    __syncthreads();
    #pragma unroll 4
    for (int j = 0; j < 64; ++j) {
      float p[4], vv[4];
      #pragma unroll
      for (int mi = 0; mi < 4; ++mi) p[mi] = kS[j][ty * 4 + mi];
      #pragma unroll
      for (int nj = 0; nj < 4; ++nj) vv[nj] = vs[j][tx * 4 + nj];
      #pragma unroll
      for (int mi = 0; mi < 4; ++mi)
        #pragma unroll
        for (int nj = 0; nj < 4; ++nj) acc[mi][nj] = fmaf(p[mi], vv[nj], acc[mi][nj]);
    }
  }
  #pragma unroll
  for (int mi = 0; mi < 4; ++mi) {
    float4 o = make_float4(acc[mi][0], acc[mi][1], acc[mi][2], acc[mi][3]);
    *reinterpret_cast<float4*>(
        &y[((size_t)b * SEQ + t0 + ty * 4 + mi) * H_DIM + h0 + tx * 4]) = o;
  }
}

// ---------------- launch ----------------------------------------------------
extern "C" void kernel_launch(void* const* d_in, const int* in_sizes, int n_in,
                              void* d_out, int out_size, void* d_ws, size_t ws_size,
                              hipStream_t stream) {
  const float* x      = (const float*)d_in[0];
  const int*   amask  = (const int*)d_in[1];
  const float* ln1_g  = (const float*)d_in[2];
  const float* ln1_b  = (const float*)d_in[3];
  const float* qkv_w  = (const float*)d_in[4];
  const float* qkv_b  = (const float*)d_in[5];
  const float* out_w  = (const float*)d_in[6];
  const float* out_b  = (const float*)d_in[7];
  const float* fh_wq  = (const float*)d_in[8];
  const float* fh_wk  = (const float*)d_in[9];
  const float* fh_wo  = (const float*)d_in[10];
  const float* ln2_g  = (const float*)d_in[11];
  const float* ln2_b  = (const float*)d_in[12];
  const float* mlp_w1 = (const float*)d_in[13];
  const float* mlp_b1 = (const float*)d_in[14];
  const float* mlp_w2 = (const float*)d_in[15];
  const float* mlp_b2 = (const float*)d_in[16];
  float* out = (float*)d_out;
  float* ws  = (float*)d_ws;

  const int ROWS = BATCH * SEQ;  // 4096
  float* qkv = ws;                    // 12,582,912
  float* h1  = ws + 12582912;         // 4,194,304 (reused as ctx)
  float* ctx = h1;
  float* x1  = ws + 16777216;         // 4,194,304
  float* qr  = ws + 20971520;         // 262,144
  float* kr  = ws + 21233664;         // 262,144
  float* yy  = ws + 21495808;         // 4,194,304
  float* x2  = ws + 25690112;         // 4,194,304
  float* h2  = ws + 29884416;         // 4,194,304
  float* g1  = ws;                    // aliases dead qkv+h1 region at step 9
  float* Gband = h2;                  // 1,048,576 (alive only steps 6-7)
  float* L_arr = h2 + 1048576;        // 4096
  // kv bf16 hi/lo: alive only during attention (step 3); alias x2 / h2 slots
  unsigned short* kvh = (unsigned short*)x2;   // 4096*2048*2B = 16.78 MB
  unsigned short* kvl = (unsigned short*)h2;   // 16.78 MB

  // 1) h1 = LN1(x)
  ln_kernel<<<ROWS, 256, 0, stream>>>(x, ln1_g, ln1_b, h1);
  // 2) qkv = h1 @ qkv_w + qkv_b                        [MFMA split-bf16]
  mgemm_kernel<0, false><<<dim3(3072 / 128, ROWS / 128), 256, 0, stream>>>(
      h1, H_DIM, qkv_w, 3 * H_DIM, qkv_b, nullptr, 0, qkv, 3 * H_DIM, ROWS, 3 * H_DIM, H_DIM);
  // 3) ctx = causal attention                          [MFMA split-bf16 flash]
  kvconv_kernel<<<ROWS * 2048 / 4 / 256, 256, 0, stream>>>(qkv, kvh, kvl);
  attn_mfma_kernel<<<dim3(SEQ / 64, NHEAD, BATCH), 256, 0, stream>>>(
      qkv, kvh, kvl, amask, ctx);
  // 4) x1 = x + ctx @ out_w + out_b                    [MFMA split-bf16]
  mgemm_kernel<0, true><<<dim3(1024 / 128, ROWS / 128), 256, 0, stream>>>(
      ctx, H_DIM, out_w, H_DIM, out_b, x, H_DIM, x1, H_DIM, ROWS, H_DIM, H_DIM);
  // 5) qr = phi(q @ fh_wq), kr = phi(k @ fh_wk)        [small: VALU path]
  gemm_kernel<128, 64, 16, 1, false><<<dim3(1, ROWS / 128), 256, 0, stream>>>(
      qkv, 3 * H_DIM, fh_wq, RDIM, nullptr, nullptr, 0, qr, RDIM, ROWS, RDIM, H_DIM);
  gemm_kernel<128, 64, 16, 1, false><<<dim3(1, ROWS / 128), 256, 0, stream>>>(
      qkv + H_DIM, 3 * H_DIM, fh_wk, RDIM, nullptr, nullptr, 0, kr, RDIM, ROWS, RDIM, H_DIM);
  // 6) banded Gram products, scalar homeostatic scan, weighted-attention y
  gram_kernel<<<dim3(5, SEQ / 64, BATCH), 256, 0, stream>>>(qkv, kr, Gband);
  fwscan_kernel<<<BATCH, 64, 0, stream>>>(Gband, L_arr);
  fwy_kernel<<<dim3(H_DIM / 64, SEQ / 64, BATCH), 256, 0, stream>>>(qkv, qr, kr, L_arr, yy);
  // 7) x2 = x1 + yy @ fh_wo                            [MFMA split-bf16]
  mgemm_kernel<0, true><<<dim3(1024 / 128, ROWS / 128), 256, 0, stream>>>(
      yy, H_DIM, fh_wo, H_DIM, nullptr, x1, H_DIM, x2, H_DIM, ROWS, H_DIM, H_DIM);
  // 8) h2 = LN2(x2)
  ln_kernel<<<ROWS, 256, 0, stream>>>(x2, ln2_g, ln2_b, h2);
  // 9) g1 = gelu(h2 @ mlp_w1 + mlp_b1)                 [MFMA split-bf16]
  mgemm_kernel<2, false><<<dim3(4096 / 128, ROWS / 128), 256, 0, stream>>>(
      h2, H_DIM, mlp_w1, MDIM, mlp_b1, nullptr, 0, g1, MDIM, ROWS, MDIM, H_DIM);
  // 10) out = x2 + g1 @ mlp_w2 + mlp_b2                [MFMA split-bf16]
  mgemm_kernel<0, true><<<dim3(1024 / 128, ROWS / 128), 256, 0, stream>>>(
      g1, MDIM, mlp_w2, H_DIM, mlp_b2, x2, H_DIM, out, H_DIM, ROWS, H_DIM, MDIM);
}

// Round 7
// 2116.785 us; speedup vs baseline: 4.4305x; 1.3032x over previous
//
#include <hip/hip_runtime.h>
#include <hip/hip_bf16.h>
#include <math.h>

// Problem constants (match reference)
#define H_DIM 1024
#define NHEAD 16
#define HDm   64
#define SEQ   2048
#define BATCH 2
#define RDIM  64
#define MDIM  4096
#define ALPHA_C 0.5f
#define BETA_C  0.1f
#define GAMMA_C 0.95f
#define LNGAMMA (-0.051293294387550533f)
#define BAND 256

typedef __attribute__((ext_vector_type(8))) short bfrag;   // 8 bf16 (4 VGPRs)
typedef __attribute__((ext_vector_type(4))) float facc;    // 4 fp32

__device__ __forceinline__ float gelu_exact(float x) {
  return 0.5f * x * (1.f + erff(x * 0.70710678118654752f));
}
__device__ __forceinline__ float phi_elu(float x) {   // elu(x)+1
  return x > 0.f ? x + 1.f : __expf(x);
}
__device__ __forceinline__ float wave_sum(float v) {
  #pragma unroll
  for (int o = 32; o > 0; o >>= 1) v += __shfl_xor(v, o, 64);
  return v;
}
__device__ __forceinline__ unsigned short f2bf(float f) {   // RNE fp32->bf16
  unsigned int u = __float_as_uint(f);
  u += 0x7fffu + ((u >> 16) & 1u);
  return (unsigned short)(u >> 16);
}
__device__ __forceinline__ float bf2f(unsigned short s) {
  return __uint_as_float(((unsigned int)s) << 16);
}
__device__ __forceinline__ float f4get(const float4& v, int i) {  // i compile-time
  return i == 0 ? v.x : i == 1 ? v.y : i == 2 ? v.z : v.w;
}

// ---------------- LayerNorm: one block per row (H=1024, 256 thr x float4) ----
__global__ __launch_bounds__(256) void ln_kernel(
    const float* __restrict__ x, const float* __restrict__ g,
    const float* __restrict__ bt, float* __restrict__ out) {
  __shared__ float lds[4];
  const int row = blockIdx.x;
  const int tid = threadIdx.x;
  const float4 v = reinterpret_cast<const float4*>(x + (size_t)row * H_DIM)[tid];
  float s = (v.x + v.y) + (v.z + v.w);
  s = wave_sum(s);
  if ((tid & 63) == 0) lds[tid >> 6] = s;
  __syncthreads();
  const float mu = (lds[0] + lds[1] + lds[2] + lds[3]) * (1.f / H_DIM);
  __syncthreads();
  float4 d;
  d.x = v.x - mu; d.y = v.y - mu; d.z = v.z - mu; d.w = v.w - mu;
  float s2 = (d.x * d.x + d.y * d.y) + (d.z * d.z + d.w * d.w);
  s2 = wave_sum(s2);
  if ((tid & 63) == 0) lds[tid >> 6] = s2;
  __syncthreads();
  const float var = (lds[0] + lds[1] + lds[2] + lds[3]) * (1.f / H_DIM);
  const float rs = rsqrtf(var + 1e-5f);
  const float4 gg = reinterpret_cast<const float4*>(g)[tid];
  const float4 bb = reinterpret_cast<const float4*>(bt)[tid];
  float4 o;
  o.x = d.x * rs * gg.x + bb.x;
  o.y = d.y * rs * gg.y + bb.y;
  o.z = d.z * rs * gg.z + bb.z;
  o.w = d.w * rs * gg.w + bb.w;
  reinterpret_cast<float4*>(out + (size_t)row * H_DIM)[tid] = o;
}

// ---------------- Split-bf16 MFMA GEMM: C = act(A@B + bias) + R -------------
#define LP 40   // LDS row pitch in ushorts (32 used + 8 pad -> 80B rows)
template <int EPI, bool RES>
__global__ __launch_bounds__(256) void mgemm_kernel(
    const float* __restrict__ A, int lda,
    const float* __restrict__ B, int ldb,
    const float* __restrict__ bias,
    const float* __restrict__ Rp, int ldr,
    float* __restrict__ C, int ldc,
    int M, int N, int K) {
  __shared__ unsigned short Ah[128 * LP], Al[128 * LP];
  __shared__ unsigned short Bh[128 * LP], Bl[128 * LP];
  const int tid = threadIdx.x;
  const int lane = tid & 63, wv = tid >> 6;
  const int wr = wv >> 1, wc = wv & 1;
  const int g = lane >> 4, lr = lane & 15;
  const int m0 = blockIdx.y * 128, n0 = blockIdx.x * 128;
  facc acc[4][4];
  #pragma unroll
  for (int i = 0; i < 4; ++i)
    #pragma unroll
    for (int j = 0; j < 4; ++j) acc[i][j] = (facc)(0.f);

  for (int k0 = 0; k0 < K; k0 += 32) {
    __syncthreads();
    #pragma unroll
    for (int it = 0; it < 4; ++it) {
      const int i = tid + it * 256;
      const int m = i >> 3, q = i & 7;
      const float4 a4 = *reinterpret_cast<const float4*>(
          A + (size_t)(m0 + m) * lda + k0 + q * 4);
      ushort4 hi, lo;
      hi.x = f2bf(a4.x); lo.x = f2bf(a4.x - bf2f(hi.x));
      hi.y = f2bf(a4.y); lo.y = f2bf(a4.y - bf2f(hi.y));
      hi.z = f2bf(a4.z); lo.z = f2bf(a4.z - bf2f(hi.z));
      hi.w = f2bf(a4.w); lo.w = f2bf(a4.w - bf2f(hi.w));
      *reinterpret_cast<ushort4*>(&Ah[m * LP + q * 4]) = hi;
      *reinterpret_cast<ushort4*>(&Al[m * LP + q * 4]) = lo;
    }
    #pragma unroll
    for (int it = 0; it < 4; ++it) {
      const int i = tid + it * 256;
      const int n = i & 127, kc = (i >> 7) * 4;
      const float* bp = B + (size_t)(k0 + kc) * ldb + n0 + n;
      const float b0 = bp[0];
      const float b1 = bp[(size_t)ldb];
      const float b2 = bp[(size_t)2 * ldb];
      const float b3 = bp[(size_t)3 * ldb];
      ushort4 hi, lo;
      hi.x = f2bf(b0); lo.x = f2bf(b0 - bf2f(hi.x));
      hi.y = f2bf(b1); lo.y = f2bf(b1 - bf2f(hi.y));
      hi.z = f2bf(b2); lo.z = f2bf(b2 - bf2f(hi.z));
      hi.w = f2bf(b3); lo.w = f2bf(b3 - bf2f(hi.w));
      *reinterpret_cast<ushort4*>(&Bh[n * LP + kc]) = hi;
      *reinterpret_cast<ushort4*>(&Bl[n * LP + kc]) = lo;
    }
    __syncthreads();
    bfrag ah[4], al[4], bh[4], bl[4];
    #pragma unroll
    for (int mi = 0; mi < 4; ++mi) {
      const int r = wr * 64 + mi * 16 + lr;
      ah[mi] = *reinterpret_cast<const bfrag*>(&Ah[r * LP + g * 8]);
      al[mi] = *reinterpret_cast<const bfrag*>(&Al[r * LP + g * 8]);
    }
    #pragma unroll
    for (int nj = 0; nj < 4; ++nj) {
      const int c = wc * 64 + nj * 16 + lr;
      bh[nj] = *reinterpret_cast<const bfrag*>(&Bh[c * LP + g * 8]);
      bl[nj] = *reinterpret_cast<const bfrag*>(&Bl[c * LP + g * 8]);
    }
    #pragma unroll
    for (int mi = 0; mi < 4; ++mi)
      #pragma unroll
      for (int nj = 0; nj < 4; ++nj) {
        acc[mi][nj] = __builtin_amdgcn_mfma_f32_16x16x32_bf16(
            ah[mi], bh[nj], acc[mi][nj], 0, 0, 0);
        acc[mi][nj] = __builtin_amdgcn_mfma_f32_16x16x32_bf16(
            ah[mi], bl[nj], acc[mi][nj], 0, 0, 0);
        acc[mi][nj] = __builtin_amdgcn_mfma_f32_16x16x32_bf16(
            al[mi], bh[nj], acc[mi][nj], 0, 0, 0);
      }
  }
  #pragma unroll
  for (int mi = 0; mi < 4; ++mi) {
    const int row0 = m0 + wr * 64 + mi * 16 + g * 4;
    #pragma unroll
    for (int nj = 0; nj < 4; ++nj) {
      const int col = n0 + wc * 64 + nj * 16 + lr;
      const float bs = bias ? bias[col] : 0.f;
      #pragma unroll
      for (int r = 0; r < 4; ++r) {
        float cv = acc[mi][nj][r] + bs;
        if (EPI == 1) cv = phi_elu(cv);
        else if (EPI == 2) cv = gelu_exact(cv);
        if (RES) cv += Rp[(size_t)(row0 + r) * ldr + col];
        C[(size_t)(row0 + r) * ldc + col] = cv;
      }
    }
  }
}

// ---------------- Generic fp32 tiled GEMM (small shapes: qr/kr) ------------
template <int BM, int BN, int BK, int EPI, bool RES>
__global__ __launch_bounds__(256) void gemm_kernel(
    const float* __restrict__ A, int lda,
    const float* __restrict__ B, int ldb,
    const float* __restrict__ bias,
    const float* __restrict__ Rp, int ldr,
    float* __restrict__ C, int ldc,
    int M, int N, int K) {
  constexpr int TM = BM / 16, TN = BN / 16;
  __shared__ float As[BK][BM + 4];
  __shared__ float Bs[BK][BN + 4];
  const int tid = threadIdx.x;
  const int tx = tid & 15, ty = tid >> 4;
  const int m0 = blockIdx.y * BM, n0 = blockIdx.x * BN;
  float acc[TM][TN];
  #pragma unroll
  for (int i = 0; i < TM; ++i)
    #pragma unroll
    for (int j = 0; j < TN; ++j) acc[i][j] = 0.f;

  for (int k0 = 0; k0 < K; k0 += BK) {
    #pragma unroll
    for (int i = tid; i < BM * BK / 4; i += 256) {
      const int m = i / (BK / 4);
      const int kq = (i % (BK / 4)) * 4;
      const int gm = m0 + m;
      float4 av = make_float4(0.f, 0.f, 0.f, 0.f);
      if (gm < M) av = *reinterpret_cast<const float4*>(A + (size_t)gm * lda + k0 + kq);
      As[kq + 0][m] = av.x;
      As[kq + 1][m] = av.y;
      As[kq + 2][m] = av.z;
      As[kq + 3][m] = av.w;
    }
    #pragma unroll
    for (int i = tid; i < BK * BN / 4; i += 256) {
      const int kk = i / (BN / 4);
      const int n = (i % (BN / 4)) * 4;
      const int gn = n0 + n;
      float4 bv = make_float4(0.f, 0.f, 0.f, 0.f);
      if (gn < N) bv = *reinterpret_cast<const float4*>(B + (size_t)(k0 + kk) * ldb + gn);
      *reinterpret_cast<float4*>(&Bs[kk][n]) = bv;
    }
    __syncthreads();
    #pragma unroll
    for (int kk = 0; kk < BK; ++kk) {
      float a[TM], b[TN];
      #pragma unroll
      for (int i = 0; i < TM; ++i) a[i] = As[kk][ty * TM + i];
      #pragma unroll
      for (int j = 0; j < TN; ++j) b[j] = Bs[kk][tx * TN + j];
      #pragma unroll
      for (int i = 0; i < TM; ++i)
        #pragma unroll
        for (int j = 0; j < TN; ++j) acc[i][j] = fmaf(a[i], b[j], acc[i][j]);
    }
    __syncthreads();
  }
  #pragma unroll
  for (int i = 0; i < TM; ++i) {
    const int gm = m0 + ty * TM + i;
    if (gm >= M) continue;
    #pragma unroll
    for (int j = 0; j < TN; ++j) {
      const int gn = n0 + tx * TN + j;
      if (gn >= N) continue;
      float c = acc[i][j];
      if (bias) c += bias[gn];
      if (EPI == 1) c = phi_elu(c);
      else if (EPI == 2) c = gelu_exact(c);
      if (RES) c += Rp[(size_t)gm * ldr + gn];
      C[(size_t)gm * ldc + gn] = c;
    }
  }
}

// ---------------- K/V fp32 -> split-bf16 pre-pass ---------------------------
__global__ __launch_bounds__(256) void kvconv_kernel(
    const float* __restrict__ qkv, unsigned short* __restrict__ kvh,
    unsigned short* __restrict__ kvl) {
  const size_t i = (size_t)blockIdx.x * 256 + threadIdx.x;  // quad index
  const int row = (int)(i >> 9);             // 512 quads per row
  const int cq = ((int)i & 511) * 4;
  const float4 v = *reinterpret_cast<const float4*>(
      qkv + (size_t)row * (3 * H_DIM) + H_DIM + cq);
  ushort4 hi, lo;
  hi.x = f2bf(v.x); lo.x = f2bf(v.x - bf2f(hi.x));
  hi.y = f2bf(v.y); lo.y = f2bf(v.y - bf2f(hi.y));
  hi.z = f2bf(v.z); lo.z = f2bf(v.z - bf2f(hi.z));
  hi.w = f2bf(v.w); lo.w = f2bf(v.w - bf2f(hi.w));
  *reinterpret_cast<ushort4*>(kvh + (size_t)row * 2048 + cq) = hi;
  *reinterpret_cast<ushort4*>(kvl + (size_t)row * 2048 + cq) = lo;
}

// ---------------- Split-bf16 MFMA flash attention ---------------------------
#define KP 72   // LDS pitch in ushorts (144B, 16B-aligned)
__global__ __launch_bounds__(256) void attn_mfma_kernel(
    const float* __restrict__ qkv, const unsigned short* __restrict__ kvh,
    const unsigned short* __restrict__ kvl, const int* __restrict__ amask,
    float* __restrict__ ctx) {
  __shared__ unsigned short Kh[64 * KP], Kl[64 * KP];   // [key][d]
  __shared__ unsigned short Vh[64 * KP], Vl[64 * KP];   // [d][key] (transposed)
  __shared__ unsigned short Ph[4][16 * KP], Pl[4][16 * KP];
  const int tid = threadIdx.x, lane = tid & 63, w = tid >> 6;
  const int g = lane >> 4, lr = lane & 15;
  const int qb = blockIdx.x, head = blockIdx.y, b = blockIdx.z;
  const int t0 = qb * 64;
  const int qrow = t0 + w * 16 + lr;
  const float* qp = qkv + ((size_t)b * SEQ + qrow) * (3 * H_DIM) + head * HDm;
  bfrag qh[2], ql[2];
  #pragma unroll
  for (int ks = 0; ks < 2; ++ks) {
    float qv[8];
    *reinterpret_cast<float4*>(&qv[0]) =
        *reinterpret_cast<const float4*>(qp + ks * 32 + g * 8);
    *reinterpret_cast<float4*>(&qv[4]) =
        *reinterpret_cast<const float4*>(qp + ks * 32 + g * 8 + 4);
    #pragma unroll
    for (int j = 0; j < 8; ++j) {
      const unsigned short h = f2bf(qv[j]);
      qh[ks][j] = (short)h;
      ql[ks][j] = (short)f2bf(qv[j] - bf2f(h));
    }
  }
  float mrow[4] = {-1e30f, -1e30f, -1e30f, -1e30f};
  float lrow[4] = {0.f, 0.f, 0.f, 0.f};
  facc oacc[4];
  #pragma unroll
  for (int nf = 0; nf < 4; ++nf) oacc[nf] = (facc)(0.f);

  for (int kt = 0; kt <= qb; ++kt) {
    const int kb = kt * 64;
    __syncthreads();
    #pragma unroll
    for (int it = 0; it < 4; ++it) {
      const int qid = tid + it * 256;
      const int key = qid >> 4, d0 = (qid & 15) * 4;
      const size_t gb = ((size_t)b * SEQ + kb + key) * 2048 + head * HDm + d0;
      const ushort4 kh4 = *reinterpret_cast<const ushort4*>(kvh + gb);
      const ushort4 kl4 = *reinterpret_cast<const ushort4*>(kvl + gb);
      *reinterpret_cast<ushort4*>(&Kh[key * KP + d0]) = kh4;
      *reinterpret_cast<ushort4*>(&Kl[key * KP + d0]) = kl4;
      const ushort4 vh4 = *reinterpret_cast<const ushort4*>(kvh + gb + H_DIM);
      const ushort4 vl4 = *reinterpret_cast<const ushort4*>(kvl + gb + H_DIM);
      Vh[(d0 + 0) * KP + key] = vh4.x; Vh[(d0 + 1) * KP + key] = vh4.y;
      Vh[(d0 + 2) * KP + key] = vh4.z; Vh[(d0 + 3) * KP + key] = vh4.w;
      Vl[(d0 + 0) * KP + key] = vl4.x; Vl[(d0 + 1) * KP + key] = vl4.y;
      Vl[(d0 + 2) * KP + key] = vl4.z; Vl[(d0 + 3) * KP + key] = vl4.w;
    }
    __syncthreads();
    facc sacc[4];
    #pragma unroll
    for (int nf = 0; nf < 4; ++nf) sacc[nf] = (facc)(0.f);
    #pragma unroll
    for (int ks = 0; ks < 2; ++ks) {
      #pragma unroll
      for (int nf = 0; nf < 4; ++nf) {
        const bfrag kbh = *reinterpret_cast<const bfrag*>(
            &Kh[(nf * 16 + lr) * KP + ks * 32 + g * 8]);
        const bfrag kbl = *reinterpret_cast<const bfrag*>(
            &Kl[(nf * 16 + lr) * KP + ks * 32 + g * 8]);
        sacc[nf] = __builtin_amdgcn_mfma_f32_16x16x32_bf16(qh[ks], kbh, sacc[nf], 0, 0, 0);
        sacc[nf] = __builtin_amdgcn_mfma_f32_16x16x32_bf16(qh[ks], kbl, sacc[nf], 0, 0, 0);
        sacc[nf] = __builtin_amdgcn_mfma_f32_16x16x32_bf16(ql[ks], kbh, sacc[nf], 0, 0, 0);
      }
    }
    float sval[4][4], tmax[4] = {-1e30f, -1e30f, -1e30f, -1e30f};
    #pragma unroll
    for (int nf = 0; nf < 4; ++nf) {
      const int key = kb + nf * 16 + lr;
      const bool am = amask[b * SEQ + key] != 0;
      #pragma unroll
      for (int r = 0; r < 4; ++r) {
        const int rq = t0 + w * 16 + g * 4 + r;
        float s = sacc[nf][r] * 0.125f;
        s = (am && key <= rq) ? s : -1e30f;
        sval[nf][r] = s;
        tmax[r] = fmaxf(tmax[r], s);
      }
    }
    #pragma unroll
    for (int o = 1; o < 16; o <<= 1)
      #pragma unroll
      for (int r = 0; r < 4; ++r) tmax[r] = fmaxf(tmax[r], __shfl_xor(tmax[r], o, 64));
    float corr[4], lsum[4] = {0.f, 0.f, 0.f, 0.f};
    #pragma unroll
    for (int r = 0; r < 4; ++r) {
      const float mn = fmaxf(mrow[r], tmax[r]);
      corr[r] = __expf(mrow[r] - mn);
      mrow[r] = mn;
    }
    #pragma unroll
    for (int nf = 0; nf < 4; ++nf)
      #pragma unroll
      for (int r = 0; r < 4; ++r) {
        const float p = (sval[nf][r] > -0.9e30f) ? __expf(sval[nf][r] - mrow[r]) : 0.f;
        lsum[r] += p;
        const unsigned short ph = f2bf(p);
        Ph[w][(g * 4 + r) * KP + nf * 16 + lr] = ph;
        Pl[w][(g * 4 + r) * KP + nf * 16 + lr] = f2bf(p - bf2f(ph));
      }
    #pragma unroll
    for (int o = 1; o < 16; o <<= 1)
      #pragma unroll
      for (int r = 0; r < 4; ++r) lsum[r] += __shfl_xor(lsum[r], o, 64);
    #pragma unroll
    for (int r = 0; r < 4; ++r) lrow[r] = lrow[r] * corr[r] + lsum[r];
    #pragma unroll
    for (int nf = 0; nf < 4; ++nf)
      #pragma unroll
      for (int r = 0; r < 4; ++r) oacc[nf][r] *= corr[r];
    #pragma unroll
    for (int ks = 0; ks < 2; ++ks) {
      const bfrag pah = *reinterpret_cast<const bfrag*>(&Ph[w][lr * KP + ks * 32 + g * 8]);
      const bfrag pal = *reinterpret_cast<const bfrag*>(&Pl[w][lr * KP + ks * 32 + g * 8]);
      #pragma unroll
      for (int nf = 0; nf < 4; ++nf) {
        const bfrag vbh = *reinterpret_cast<const bfrag*>(
            &Vh[(nf * 16 + lr) * KP + ks * 32 + g * 8]);
        const bfrag vbl = *reinterpret_cast<const bfrag*>(
            &Vl[(nf * 16 + lr) * KP + ks * 32 + g * 8]);
        oacc[nf] = __builtin_amdgcn_mfma_f32_16x16x32_bf16(pah, vbh, oacc[nf], 0, 0, 0);
        oacc[nf] = __builtin_amdgcn_mfma_f32_16x16x32_bf16(pah, vbl, oacc[nf], 0, 0, 0);
        oacc[nf] = __builtin_amdgcn_mfma_f32_16x16x32_bf16(pal, vbh, oacc[nf], 0, 0, 0);
      }
    }
  }
  float* op = ctx + ((size_t)b * SEQ + t0 + w * 16) * H_DIM + head * HDm;
  #pragma unroll
  for (int nf = 0; nf < 4; ++nf)
    #pragma unroll
    for (int r = 0; r < 4; ++r)
      op[(size_t)(g * 4 + r) * H_DIM + nf * 16 + lr] =
          oacc[nf][r] / fmaxf(lrow[r], 1e-30f);
}

// ---------------- Fast-weights: banded Gram products ------------------------
__global__ __launch_bounds__(256) void gram_kernel(
    const float* __restrict__ qkv, const float* __restrict__ kr,
    float* __restrict__ Gband) {
  __shared__ float As[16][68], Bs[16][68];
  const int b = blockIdx.z, t0 = blockIdx.y * 64;
  const int tau0 = t0 - BAND + blockIdx.x * 64;
  if (tau0 < 0) return;
  const int tid = threadIdx.x, tx = tid & 15, ty = tid >> 4;
  const float* vb = qkv + (size_t)b * SEQ * (3 * H_DIM) + 2 * H_DIM;
  const float* kb = kr + (size_t)b * SEQ * RDIM;
  float accV[4][4] = {{0.f}}, accK[4][4] = {{0.f}};
  const int m = tid >> 2, kq = (tid & 3) * 4;
  for (int chunk = 0; chunk < 68; ++chunk) {
    __syncthreads();
    if (chunk < 64) {
      const int k0 = chunk * 16;
      const float4 a4 = *reinterpret_cast<const float4*>(vb + (size_t)(t0 + m) * (3 * H_DIM) + k0 + kq);
      const float4 b4 = *reinterpret_cast<const float4*>(vb + (size_t)(tau0 + m) * (3 * H_DIM) + k0 + kq);
      As[kq + 0][m] = a4.x; As[kq + 1][m] = a4.y; As[kq + 2][m] = a4.z; As[kq + 3][m] = a4.w;
      Bs[kq + 0][m] = b4.x; Bs[kq + 1][m] = b4.y; Bs[kq + 2][m] = b4.z; Bs[kq + 3][m] = b4.w;
    } else {
      const int k0 = (chunk - 64) * 16;
      const float4 a4 = *reinterpret_cast<const float4*>(kb + (size_t)(t0 + m) * RDIM + k0 + kq);
      const float4 b4 = *reinterpret_cast<const float4*>(kb + (size_t)(tau0 + m) * RDIM + k0 + kq);
      As[kq + 0][m] = a4.x; As[kq + 1][m] = a4.y; As[kq + 2][m] = a4.z; As[kq + 3][m] = a4.w;
      Bs[kq + 0][m] = b4.x; Bs[kq + 1][m] = b4.y; Bs[kq + 2][m] = b4.z; Bs[kq + 3][m] = b4.w;
    }
    __syncthreads();
    #pragma unroll
    for (int kk = 0; kk < 16; ++kk) {
      float a[4], bb[4];
      #pragma unroll
      for (int i = 0; i < 4; ++i) a[i] = As[kk][ty * 4 + i];
      #pragma unroll
      for (int j = 0; j < 4; ++j) bb[j] = Bs[kk][tx * 4 + j];
      if (chunk < 64) {
        #pragma unroll
        for (int i = 0; i < 4; ++i)
          #pragma unroll
          for (int j = 0; j < 4; ++j) accV[i][j] = fmaf(a[i], bb[j], accV[i][j]);
      } else {
        #pragma unroll
        for (int i = 0; i < 4; ++i)
          #pragma unroll
          for (int j = 0; j < 4; ++j) accK[i][j] = fmaf(a[i], bb[j], accK[i][j]);
      }
    }
  }
  #pragma unroll
  for (int i = 0; i < 4; ++i) {
    const int t = t0 + ty * 4 + i;
    #pragma unroll
    for (int j = 0; j < 4; ++j) {
      const int tau = tau0 + tx * 4 + j;
      const int lag = t - tau;
      if (lag >= 0 && lag < BAND)
        Gband[((size_t)b * SEQ + t) * BAND + (tau & (BAND - 1))] = accK[i][j] * accV[i][j];
    }
  }
}

// ---------------- Fast-weights: chunked homeostatic scan --------------------
// 1 wave per batch, chunk of 8 steps. Heavy 256-dot reductions are hoisted:
// d[j] = <u_chunk_start, G[t+j]> computed+reduced together (8 indep chains),
// then 8 serial scalar steps use cross_j = P_j*d_j + sum_i c_i*tri[j][i]
// (tri = wave-uniform 8x8 sub-band triangle). Expiry leak terms carry weight
// <= gamma^255 ~ 2e-6 * tiny products -> below fp32 noise (same threshold as
// the BAND=256 truncation itself).
__device__ __forceinline__ void fw_load(const float* __restrict__ gb, int tc,
                                        int lane, float4 (&row)[8],
                                        float4 (&tq)[8][2]) {
  const float* rb = gb + (size_t)tc * BAND;
  const int cbase = tc & (BAND - 1);          // multiple of 8 -> never wraps
  #pragma unroll
  for (int j = 0; j < 8; ++j) {
    row[j] = *reinterpret_cast<const float4*>(rb + (size_t)j * BAND + lane * 4);
    tq[j][0] = *reinterpret_cast<const float4*>(rb + (size_t)j * BAND + cbase);
    tq[j][1] = *reinterpret_cast<const float4*>(rb + (size_t)j * BAND + cbase + 4);
  }
}

__device__ __forceinline__ void fw_chunk(int tc, int lane, int b,
    const float4 (&row)[8], const float4 (&tq)[8][2],
    float (&u)[4], float& n, float& L, float* __restrict__ L_arr) {
  float d[8];
  #pragma unroll
  for (int j = 0; j < 8; ++j)
    d[j] = u[0] * row[j].x + u[1] * row[j].y + u[2] * row[j].z + u[3] * row[j].w;
  #pragma unroll
  for (int o = 1; o < 64; o <<= 1) {
    #pragma unroll
    for (int j = 0; j < 8; ++j) d[j] += __shfl_xor(d[j], o, 64);
  }
  float P = 1.f;
  float c[8];
  #pragma unroll
  for (int j = 0; j < 8; ++j) {
    float cross = P * d[j];
    #pragma unroll
    for (int i = 0; i < j; ++i) cross += c[i] * f4get(tq[j][i >> 2], i & 3);
    float np = GAMMA_C * GAMMA_C * n + 2.f * GAMMA_C * ALPHA_C * cross
             + ALPHA_C * ALPHA_C * f4get(tq[j][j >> 2], j & 3);
    np = fmaxf(np, 0.f);
    const float s = __fdividef(1.f, fmaf(BETA_C, sqrtf(np), 1.f));
    n = s * s * np;
    L += __logf(s);
    if (lane == 0) L_arr[(size_t)b * SEQ + tc + j] = L;
    const float gs = GAMMA_C * s;
    P *= gs;
    #pragma unroll
    for (int i = 0; i < j; ++i) c[i] *= gs;
    c[j] = ALPHA_C * s;
  }
  #pragma unroll
  for (int e = 0; e < 4; ++e) u[e] *= P;
  const int basel = (tc & (BAND - 1)) >> 2;
  if (lane == basel)     { u[0] = c[0]; u[1] = c[1]; u[2] = c[2]; u[3] = c[3]; }
  if (lane == basel + 1) { u[0] = c[4]; u[1] = c[5]; u[2] = c[6]; u[3] = c[7]; }
}

__global__ __launch_bounds__(64) void fwscan_kernel(
    const float* __restrict__ Gband, float* __restrict__ L_arr) {
  const int b = blockIdx.x, lane = threadIdx.x;
  const float* gb = Gband + (size_t)b * SEQ * BAND;
  float u[4] = {0.f, 0.f, 0.f, 0.f};
  float n = 0.f, L = 0.f;
  float4 rA[8], rB[8], tA[8][2], tB[8][2];
  fw_load(gb, 0, lane, rA, tA);
  for (int tc = 0; tc < SEQ; tc += 16) {
    fw_load(gb, tc + 8, lane, rB, tB);            // prefetch next chunk
    fw_chunk(tc, lane, b, rA, tA, u, n, L, L_arr);
    const int tn = (tc + 16 < SEQ) ? tc + 16 : 0; // tail: dummy (unused) reload
    fw_load(gb, tn, lane, rA, tA);
    fw_chunk(tc + 8, lane, b, rB, tB, u, n, L, L_arr);
  }
}

// ---------------- Fast-weights: banded weighted attention y -----------------
__global__ __launch_bounds__(256) void fwy_kernel(
    const float* __restrict__ qkv, const float* __restrict__ qr,
    const float* __restrict__ kr, const float* __restrict__ L_arr,
    float* __restrict__ y) {
  __shared__ float qrT[64][68];
  __shared__ float kS[64][68];
  __shared__ float vs[64][64];
  const int b = blockIdx.z, t0 = blockIdx.y * 64, h0 = blockIdx.x * 64;
  const int tid = threadIdx.x, tx = tid & 15, ty = tid >> 4;
  const float* vbase = qkv + (size_t)b * SEQ * (3 * H_DIM) + 2 * H_DIM;
  const float* qrb = qr + (size_t)b * SEQ * RDIM;
  const float* krb = kr + (size_t)b * SEQ * RDIM;
  const float* Lb = L_arr + b * SEQ;
  #pragma unroll
  for (int it = 0; it < 4; ++it) {
    const int idx = tid + it * 256;
    const int i = idx >> 4, rq = (idx & 15) * 4;
    const float4 q4 = *reinterpret_cast<const float4*>(qrb + (size_t)(t0 + i) * RDIM + rq);
    qrT[rq + 0][i] = q4.x; qrT[rq + 1][i] = q4.y; qrT[rq + 2][i] = q4.z; qrT[rq + 3][i] = q4.w;
  }
  float Lt[4];
  #pragma unroll
  for (int mi = 0; mi < 4; ++mi) Lt[mi] = Lb[t0 + ty * 4 + mi];
  float acc[4][4];
  #pragma unroll
  for (int i = 0; i < 4; ++i)
    #pragma unroll
    for (int j = 0; j < 4; ++j) acc[i][j] = 0.f;

  for (int kt = 0; kt < 5; ++kt) {
    const int tau0 = t0 - BAND + kt * 64;
    if (tau0 < 0) continue;
    __syncthreads();
    #pragma unroll
    for (int it = 0; it < 4; ++it) {
      const int idx = tid + it * 256;
      const int j = idx >> 4, rq = (idx & 15) * 4;
      const float4 k4 = *reinterpret_cast<const float4*>(krb + (size_t)(tau0 + j) * RDIM + rq);
      kS[rq + 0][j] = k4.x; kS[rq + 1][j] = k4.y; kS[rq + 2][j] = k4.z; kS[rq + 3][j] = k4.w;
    }
    #pragma unroll
    for (int it = 0; it < 4; ++it) {
      const int idx = tid + it * 256;
      const int j = idx >> 4, hq = (idx & 15) * 4;
      *reinterpret_cast<float4*>(&vs[j][hq]) =
          *reinterpret_cast<const float4*>(vbase + (size_t)(tau0 + j) * (3 * H_DIM) + h0 + hq);
    }
    __syncthreads();
    float sacc[4][4];
    #pragma unroll
    for (int i = 0; i < 4; ++i)
      #pragma unroll
      for (int j = 0; j < 4; ++j) sacc[i][j] = 0.f;
    #pragma unroll 4
    for (int r = 0; r < 64; ++r) {
      float a[4], bb[4];
      #pragma unroll
      for (int i = 0; i < 4; ++i) a[i] = qrT[r][ty * 4 + i];
      #pragma unroll
      for (int j = 0; j < 4; ++j) bb[j] = kS[r][tx * 4 + j];
      #pragma unroll
      for (int i = 0; i < 4; ++i)
        #pragma unroll
        for (int j = 0; j < 4; ++j) sacc[i][j] = fmaf(a[i], bb[j], sacc[i][j]);
    }
    __syncthreads();
    #pragma unroll
    for (int mi = 0; mi < 4; ++mi) {
      const int t = t0 + ty * 4 + mi;
      #pragma unroll
      for (int nj = 0; nj < 4; ++nj) {
        const int tau = tau0 + tx * 4 + nj;
        const int lag = t - tau;
        float w = 0.f;
        if (lag >= 0 && lag < BAND) {
          const float Ltau = (tau > 0) ? Lb[tau - 1] : 0.f;
          w = ALPHA_C * __expf(fmaf((float)lag, LNGAMMA, Lt[mi] - Ltau)) * sacc[mi][nj];
        }
        kS[tx * 4 + nj][ty * 4 + mi] = w;
      }
    }
    __syncthreads();
    #pragma unroll 4
    for (int j = 0; j < 64; ++j) {
      float p[4], vv[4];
      #pragma unroll
      for (int mi = 0; mi < 4; ++mi) p[mi] = kS[j][ty * 4 + mi];
      #pragma unroll
      for (int nj = 0; nj < 4; ++nj) vv[nj] = vs[j][tx * 4 + nj];
      #pragma unroll
      for (int mi = 0; mi < 4; ++mi)
        #pragma unroll
        for (int nj = 0; nj < 4; ++nj) acc[mi][nj] = fmaf(p[mi], vv[nj], acc[mi][nj]);
    }
  }
  #pragma unroll
  for (int mi = 0; mi < 4; ++mi) {
    float4 o = make_float4(acc[mi][0], acc[mi][1], acc[mi][2], acc[mi][3]);
    *reinterpret_cast<float4*>(
        &y[((size_t)b * SEQ + t0 + ty * 4 + mi) * H_DIM + h0 + tx * 4]) = o;
  }
}

// ---------------- launch ----------------------------------------------------
extern "C" void kernel_launch(void* const* d_in, const int* in_sizes, int n_in,
                              void* d_out, int out_size, void* d_ws, size_t ws_size,
                              hipStream_t stream) {
  const float* x      = (const float*)d_in[0];
  const int*   amask  = (const int*)d_in[1];
  const float* ln1_g  = (const float*)d_in[2];
  const float* ln1_b  = (const float*)d_in[3];
  const float* qkv_w  = (const float*)d_in[4];
  const float* qkv_b  = (const float*)d_in[5];
  const float* out_w  = (const float*)d_in[6];
  const float* out_b  = (const float*)d_in[7];
  const float* fh_wq  = (const float*)d_in[8];
  const float* fh_wk  = (const float*)d_in[9];
  const float* fh_wo  = (const float*)d_in[10];
  const float* ln2_g  = (const float*)d_in[11];
  const float* ln2_b  = (const float*)d_in[12];
  const float* mlp_w1 = (const float*)d_in[13];
  const float* mlp_b1 = (const float*)d_in[14];
  const float* mlp_w2 = (const float*)d_in[15];
  const float* mlp_b2 = (const float*)d_in[16];
  float* out = (float*)d_out;
  float* ws  = (float*)d_ws;

  const int ROWS = BATCH * SEQ;  // 4096
  float* qkv = ws;                    // 12,582,912
  float* h1  = ws + 12582912;         // 4,194,304 (reused as ctx)
  float* ctx = h1;
  float* x1  = ws + 16777216;         // 4,194,304
  float* qr  = ws + 20971520;         // 262,144
  float* kr  = ws + 21233664;         // 262,144
  float* yy  = ws + 21495808;         // 4,194,304
  float* x2  = ws + 25690112;         // 4,194,304
  float* h2  = ws + 29884416;         // 4,194,304
  float* g1  = ws;                    // aliases dead qkv+h1 region at step 9
  float* Gband = h2;                  // 1,048,576 (alive only steps 6-7)
  float* L_arr = h2 + 1048576;        // 4096
  unsigned short* kvh = (unsigned short*)x2;   // alive only during attention
  unsigned short* kvl = (unsigned short*)h2;

  // 1) h1 = LN1(x)
  ln_kernel<<<ROWS, 256, 0, stream>>>(x, ln1_g, ln1_b, h1);
  // 2) qkv = h1 @ qkv_w + qkv_b                        [MFMA split-bf16]
  mgemm_kernel<0, false><<<dim3(3072 / 128, ROWS / 128), 256, 0, stream>>>(
      h1, H_DIM, qkv_w, 3 * H_DIM, qkv_b, nullptr, 0, qkv, 3 * H_DIM, ROWS, 3 * H_DIM, H_DIM);
  // 3) ctx = causal attention                          [MFMA split-bf16 flash]
  kvconv_kernel<<<ROWS * 2048 / 4 / 256, 256, 0, stream>>>(qkv, kvh, kvl);
  attn_mfma_kernel<<<dim3(SEQ / 64, NHEAD, BATCH), 256, 0, stream>>>(
      qkv, kvh, kvl, amask, ctx);
  // 4) x1 = x + ctx @ out_w + out_b                    [MFMA split-bf16]
  mgemm_kernel<0, true><<<dim3(1024 / 128, ROWS / 128), 256, 0, stream>>>(
      ctx, H_DIM, out_w, H_DIM, out_b, x, H_DIM, x1, H_DIM, ROWS, H_DIM, H_DIM);
  // 5) qr = phi(q @ fh_wq), kr = phi(k @ fh_wk)        [small: VALU path]
  gemm_kernel<128, 64, 16, 1, false><<<dim3(1, ROWS / 128), 256, 0, stream>>>(
      qkv, 3 * H_DIM, fh_wq, RDIM, nullptr, nullptr, 0, qr, RDIM, ROWS, RDIM, H_DIM);
  gemm_kernel<128, 64, 16, 1, false><<<dim3(1, ROWS / 128), 256, 0, stream>>>(
      qkv + H_DIM, 3 * H_DIM, fh_wk, RDIM, nullptr, nullptr, 0, kr, RDIM, ROWS, RDIM, H_DIM);
  // 6) banded Gram products, chunked homeostatic scan, weighted-attention y
  gram_kernel<<<dim3(5, SEQ / 64, BATCH), 256, 0, stream>>>(qkv, kr, Gband);
  fwscan_kernel<<<BATCH, 64, 0, stream>>>(Gband, L_arr);
  fwy_kernel<<<dim3(H_DIM / 64, SEQ / 64, BATCH), 256, 0, stream>>>(qkv, qr, kr, L_arr, yy);
  // 7) x2 = x1 + yy @ fh_wo                            [MFMA split-bf16]
  mgemm_kernel<0, true><<<dim3(1024 / 128, ROWS / 128), 256, 0, stream>>>(
      yy, H_DIM, fh_wo, H_DIM, nullptr, x1, H_DIM, x2, H_DIM, ROWS, H_DIM, H_DIM);
  // 8) h2 = LN2(x2)
  ln_kernel<<<ROWS, 256, 0, stream>>>(x2, ln2_g, ln2_b, h2);
  // 9) g1 = gelu(h2 @ mlp_w1 + mlp_b1)                 [MFMA split-bf16]
  mgemm_kernel<2, false><<<dim3(4096 / 128, ROWS / 128), 256, 0, stream>>>(
      h2, H_DIM, mlp_w1, MDIM, mlp_b1, nullptr, 0, g1, MDIM, ROWS, MDIM, H_DIM);
  // 10) out = x2 + g1 @ mlp_w2 + mlp_b2                [MFMA split-bf16]
  mgemm_kernel<0, true><<<dim3(1024 / 128, ROWS / 128), 256, 0, stream>>>(
      g1, MDIM, mlp_w2, H_DIM, mlp_b2, x2, H_DIM, out, H_DIM, ROWS, H_DIM, MDIM);
}